// Round 16
// baseline (182.198 us; speedup 1.0000x reference)
//
#include <hip/hip_runtime.h>
#include <math.h>

// Problem constants
#define BB    8
#define CIN   16
#define SS    1024
#define EE    128
#define HH    8
#define DHH   16
#define O1    512      // E*4
#define DFFN  512
#define K2TOT 8192     // O1*CIN

// Workspace layout (float offsets)
#define PE_OFF    0            // 131072  (S*E)
#define BN1SC_OFF 131072       // 512 (unused; kept)
#define BN1SH_OFF 131584       // 512
#define BN2SC_OFF 132096       // 128
#define BN2SH_OFF 132224       // 128
#define W1P_OFF   133120       // bf16 folded conv1 taps [512 o][8 u] (sc folded, slot7=0)
#define WQKV_BF_OFF 135168     // bf16 wq|wk|wv, each 16384 elems
#define W1FF_BF_OFF 159744     // bf16 ff_w1 [4nb][2kb][128][64]
#define W2FF_BF_OFF 192512     // bf16 ff_w2 [8kb][128][64]
#define XSRC_OFF  262144       // 1048576 (B*S*E) fp32 | k1 partial P7
#define Q_OFF     1310720      // QH: f16 scaled        | k1 partial P0
#define KK_OFF    2359296      // KH                    | k1 partial P1
#define V_OFF     3407872      // VHT                   | k1 partial P2
#define ATTN_OFF  4456448      // (B,S,E) attn out      | k1 partial P3
#define ATT_OFF   5505024      // (B,S,E) post-LN1      | k1 partial P4
#define FFH_OFF   6553600      // k5 bf16 out (2M)      | k1 partials P5,P6
#define W2CONV_BF_OFF 8650752  // bf16 conv2_w, K-PERM pi: o=kb*4+(g>>2)*2+(j&1), c=(g&3)*4+(j>>1)
// end: 9175040 floats = 36.7 MB
// NOTE: k1 writes 8 fp32 partials into XSRC/Q/K/V/ATTN/ATT/FFH regions; k1b
// combines into XSRC (P7 read+overwrite is same-thread-same-index, safe)
// before k2..k6 use those regions. Launch order guarantees safety.

typedef __attribute__((ext_vector_type(8))) short short8;
typedef __attribute__((ext_vector_type(8))) unsigned short ushort8;
typedef __attribute__((ext_vector_type(4))) unsigned short us4;
typedef __attribute__((ext_vector_type(4))) float f32x4;
typedef _Float16 f16_t;
typedef __attribute__((ext_vector_type(4))) _Float16 half4;
typedef __attribute__((ext_vector_type(8))) _Float16 half8;

__device__ __forceinline__ float wave_sum(float v) {
    #pragma unroll
    for (int o = 32; o > 0; o >>= 1) v += __shfl_xor(v, o);
    return v;
}

__device__ __forceinline__ float gelu_exact(float x) {
    return 0.5f * x * (1.0f + erff(x * 0.7071067811865476f));
}

// x - x/(1+exp(2*inner)), constants pre-doubled
__device__ __forceinline__ float gelu_tanh(float x) {
    float x2 = x * x;
    float y = x * fmaf(0.0713548162f, x2, 1.5957691216f);
    float E = __expf(y);
    float r = __builtin_amdgcn_rcpf(E + 1.0f);
    return fmaf(-x, r, x);
}

__device__ __forceinline__ unsigned short f2bf(float f) {   // RNE fp32->bf16
    unsigned int u = __float_as_uint(f);
    unsigned int r = u + 0x7FFFu + ((u >> 16) & 1u);
    return (unsigned short)(r >> 16);
}

__device__ __forceinline__ float bf2f(unsigned short u) {
    return __uint_as_float(((unsigned int)u) << 16);
}

// generic weight cast fp32 -> bf16, chunk-major, pre-swizzled (m173 pattern)
__device__ __forceinline__ void castw_body(const float* __restrict__ src,
                                           unsigned short* __restrict__ dst, int K, int tid) {
    int g = tid & 7, e = (tid >> 3) & 127, rest = tid >> 10;
    int KB = K >> 6;
    int kb = rest % KB, nb = rest / KB;
    int col = nb * 128 + e;
    const float* s = src + (size_t)col * K + kb * 64 + ((g ^ (e & 7)) << 3);
    ushort8 v;
    #pragma unroll
    for (int j = 0; j < 8; j++) v[j] = f2bf(s[j]);
    *(ushort8*)&dst[(size_t)tid << 3] = v;
}

// ---------------- K0: ALL setup jobs fused (independent; branch on blockIdx) ----------------
__global__ __launch_bounds__(256) void k0_all(const float* __restrict__ conv1_w,
                                              const float* __restrict__ conv1_b,
                                              const float* __restrict__ bn1_g,
                                              const float* __restrict__ bn1_b,
                                              const float* __restrict__ bn1_m,
                                              const float* __restrict__ bn1_v,
                                              const float* __restrict__ conv2_w,
                                              const float* __restrict__ conv2_b,
                                              const float* __restrict__ bn2_g,
                                              const float* __restrict__ bn2_b,
                                              const float* __restrict__ bn2_m,
                                              const float* __restrict__ bn2_v,
                                              const float* __restrict__ wq,
                                              const float* __restrict__ wk,
                                              const float* __restrict__ wv,
                                              const float* __restrict__ ff_w1,
                                              const float* __restrict__ ff_w2,
                                              float* __restrict__ ws) {
    int bid = blockIdx.x, t = threadIdx.x;
    if (bid < 512) {                       // PE table
        int idx = bid * 256 + t;
        int s = idx >> 7, e = idx & 127;
        int i = e >> 1;
        float freq = expf((float)(2 * i) * (-9.210340371976184f / 128.0f));
        float ang = (float)s * freq * 0.125f;
        ws[PE_OFF + idx] = (e & 1) ? cosf(ang) : sinf(ang);
    } else if (bid < 515) {                // BN fold
        int u = (bid - 512) * 256 + t;
        if (u < 512) {
            float sc = bn1_g[u] * rsqrtf(bn1_v[u] + 1e-5f);
            ws[BN1SC_OFF + u] = sc;
            ws[BN1SH_OFF + u] = (conv1_b[u] - bn1_m[u]) * sc + bn1_b[u];
        } else if (u < 640) {
            int e = u - 512;
            float sc = bn2_g[e] * rsqrtf(bn2_v[e] + 1e-5f);
            ws[BN2SC_OFF + e] = sc;
            ws[BN2SH_OFF + e] = (conv2_b[e] - bn2_m[e]) * sc + bn2_b[e];
        }
    } else if (bid < 1027) {               // conv2_w cast, K-PERM pi (see layout comment)
        int tid = (bid - 515) * 256 + t;   // 131072 = 128kb * 128e * 8g
        int g = tid & 7, e = (tid >> 3) & 127, kb = tid >> 10;
        int gg = g ^ (e & 7);              // source group (swizzle baked in)
        int o0 = (kb << 2) + ((gg >> 2) << 1);
        int c0 = (gg & 3) << 2;
        const float* s = conv2_w + (size_t)e * K2TOT;
        ushort8 v;
        #pragma unroll
        for (int j = 0; j < 8; j++)
            v[j] = f2bf(s[(o0 + (j & 1)) * 16 + c0 + (j >> 1)]);
        *(ushort8*)&((unsigned short*)(ws + W2CONV_BF_OFF))[(size_t)tid << 3] = v;
    } else if (bid < 1035) {
        castw_body(wq, (unsigned short*)(ws + WQKV_BF_OFF), 128, (bid - 1027) * 256 + t);
    } else if (bid < 1043) {
        castw_body(wk, (unsigned short*)(ws + WQKV_BF_OFF) + 16384, 128, (bid - 1035) * 256 + t);
    } else if (bid < 1051) {
        castw_body(wv, (unsigned short*)(ws + WQKV_BF_OFF) + 32768, 128, (bid - 1043) * 256 + t);
    } else if (bid < 1083) {
        castw_body(ff_w1, (unsigned short*)(ws + W1FF_BF_OFF), 128, (bid - 1051) * 256 + t);
    } else if (bid < 1115) {
        castw_body(ff_w2, (unsigned short*)(ws + W2FF_BF_OFF), 512, (bid - 1083) * 256 + t);
    } else {                               // folded bf16 conv1 taps: w1p[o][u] = w1[o][u]*sc1[o]
        unsigned short* w1p = (unsigned short*)(ws + W1P_OFF);
        for (int id = t; id < 4096; id += 256) {
            int o = id >> 3, u = id & 7;
            float sc = bn1_g[o] * rsqrtf(bn1_v[o] + 1e-5f);
            float v = (u < 7) ? conv1_w[o * 7 + u] * sc : 0.f;
            w1p[id] = f2bf(v);
        }
    }
}

__constant__ size_t k1_part_off[8] = {
    Q_OFF, KK_OFF, V_OFF, ATTN_OFF, ATT_OFF,
    FFH_OFF, FFH_OFF + 1048576, XSRC_OFF
};

// ---------------- K1: fused conv1+bn1+gelu -> conv2 (bf16 MFMA), barrier-free, K-perm -------
// pi: fragment element j at (kbl, ks2, lq) = h1[row][o = kbl*4+ks2*2+(j&1)][c = lq*4+(j>>1)].
// xv[28] tap regs (4 c's/lane). BM=64, 4 waves x full 128-e stripe (acc[8], no A-dup).
// FINE B-INTERLEAVE: 4-frag batches, max 8 B-frags (32 VGPR) in flight (was 16/64 ->
// 148 unified regs -> 2 waves/SIMD). Target <=128 -> __launch_bounds__(256,4).
// K-split x8 -> grid (128,8) = 4 blocks/CU = 16 waves/CU. Partials to 8 regions.
__global__ __launch_bounds__(256, 4) void k1_mfma(const float* __restrict__ x,
                                                  float* __restrict__ ws) {
    __shared__ float xt[CIN][72];                 // 4.5KB: x[b,c, s0-3 .. s0+66]
    __shared__ unsigned short w1ps[64 * 8];       // 1KB: this K-eighth's 64 o-rows
    __shared__ float sh1s[64];                    // 0.25KB

    const int t = threadIdx.x;
    const int wave = t >> 6, lane = t & 63;
    const int row0 = blockIdx.x * 64;
    const int ksplit = blockIdx.y;                // K-eighth
    const int b = row0 >> 10, s0 = row0 & 1023;
    const int obase = ksplit * 64;

    for (int i = t; i < CIN * 70; i += 256) {
        int c = i / 70, j = i % 70;
        int gs = s0 + j - 3;
        xt[c][j] = (gs >= 0 && gs < SS) ? x[(b * CIN + c) * SS + gs] : 0.f;
    }
    if (t < 64) {
        *(ushort8*)&w1ps[t << 3] =
            ((const ushort8*)((const unsigned short*)(ws + W1P_OFF)))[obase + t];
        sh1s[t] = ws[BN1SH_OFF + obase + t];
    }
    __syncthreads();                              // the ONLY barrier

    const int lrow = lane & 15, lq = lane >> 4;
    const int srow_local = (wave << 4) + lrow;    // 0..63
    const int cbase = lq << 2;                    // 4 c's per lane

    // hoist the 28 x-taps (4 c x 7 u) for this lane's fixed row
    float xv[28];
    #pragma unroll
    for (int c4 = 0; c4 < 4; ++c4)
        #pragma unroll
        for (int u = 0; u < 7; ++u)
            xv[c4 * 7 + u] = xt[cbase + c4][srow_local + u];

    // lane-constant B byte offsets (ks2=0); ks2=1 toggles bit6 (G += 4 under XOR swizzle)
    int boff[8];
    #pragma unroll
    for (int nf = 0; nf < 8; ++nf) {
        int e = (nf << 4) + lrow;
        boff[nf] = (e << 7) + ((lq ^ (e & 7)) << 4);
    }

    const char* w2g = (const char*)(ws + W2CONV_BF_OFF);

    auto computeA = [&](int kbl, int ks2) -> short8 {
        int o0 = (kbl << 2) + (ks2 << 1);         // local o base (even), 0..63
        ushort8 wa = *(const ushort8*)&w1ps[o0 << 3];
        ushort8 wb = *(const ushort8*)&w1ps[(o0 + 1) << 3];
        float sha = sh1s[o0], shb = sh1s[o0 + 1];
        short8 a;
        #pragma unroll
        for (int jh = 0; jh < 4; ++jh) {          // j = 2*jh (+1): c = cbase+jh, o = o0 (+1)
            const float* xp = &xv[jh * 7];
            float pe = xp[0]*bf2f(wa[0]) + xp[1]*bf2f(wa[1]) + xp[2]*bf2f(wa[2])
                     + xp[3]*bf2f(wa[3]) + xp[4]*bf2f(wa[4]) + xp[5]*bf2f(wa[5])
                     + xp[6]*bf2f(wa[6]);
            float po = xp[0]*bf2f(wb[0]) + xp[1]*bf2f(wb[1]) + xp[2]*bf2f(wb[2])
                     + xp[3]*bf2f(wb[3]) + xp[4]*bf2f(wb[4]) + xp[5]*bf2f(wb[5])
                     + xp[6]*bf2f(wb[6]);
            a[2 * jh]     = (short)f2bf(gelu_tanh(pe + sha));
            a[2 * jh + 1] = (short)f2bf(gelu_tanh(po + shb));
        }
        return a;
    };

    f32x4 acc[8];
    #pragma unroll
    for (int i = 0; i < 8; ++i) acc[i] = (f32x4){0.f, 0.f, 0.f, 0.f};

    #pragma unroll 1
    for (int kbl = 0; kbl < 16; ++kbl) {
        const char* g = w2g + ((size_t)((ksplit << 4) + kbl) << 14);
        // batch pipeline: never more than 8 B-frags (32 VGPR) in flight
        short8 bA_[4], bB_[4];
        #pragma unroll
        for (int i = 0; i < 4; ++i) bA_[i] = *(const short8*)(g + boff[i]);
        short8 a0 = computeA(kbl, 0);             // VALU overlaps loads
        #pragma unroll
        for (int i = 0; i < 4; ++i) bB_[i] = *(const short8*)(g + boff[4 + i]);
        #pragma unroll
        for (int nf = 0; nf < 4; ++nf)
            acc[nf] = __builtin_amdgcn_mfma_f32_16x16x32_bf16(a0, bA_[nf], acc[nf], 0, 0, 0);
        short8 bC_[4];
        #pragma unroll
        for (int i = 0; i < 4; ++i) bC_[i] = *(const short8*)(g + (boff[i] ^ 64));
        #pragma unroll
        for (int nf = 0; nf < 4; ++nf)
            acc[4 + nf] = __builtin_amdgcn_mfma_f32_16x16x32_bf16(a0, bB_[nf], acc[4 + nf], 0, 0, 0);
        short8 a1 = computeA(kbl, 1);
        short8 bD_[4];
        #pragma unroll
        for (int i = 0; i < 4; ++i) bD_[i] = *(const short8*)(g + (boff[4 + i] ^ 64));
        #pragma unroll
        for (int nf = 0; nf < 4; ++nf)
            acc[nf] = __builtin_amdgcn_mfma_f32_16x16x32_bf16(a1, bC_[nf], acc[nf], 0, 0, 0);
        #pragma unroll
        for (int nf = 0; nf < 4; ++nf)
            acc[4 + nf] = __builtin_amdgcn_mfma_f32_16x16x32_bf16(a1, bD_[nf], acc[4 + nf], 0, 0, 0);
    }

    // store fp32 partial (no bn2/gelu yet)
    float* P = ws + k1_part_off[ksplit];
    #pragma unroll
    for (int nf = 0; nf < 8; ++nf) {
        int e = (nf << 4) + lrow;
        #pragma unroll
        for (int r = 0; r < 4; ++r) {
            int srow = s0 + (wave << 4) + (lq << 2) + r;
            P[(((size_t)(b * SS + srow)) << 7) + e] = acc[nf][r];
        }
    }
}

// ---------------- K1b: combine 8 partials + bn2 + exact gelu -> x_src ----------------
__global__ __launch_bounds__(256) void k1b_combine(float* __restrict__ ws) {
    int f = (blockIdx.x * 256 + threadIdx.x) * 4;   // 1M elems
    int e0 = f & 127;
    float4 s01, s23, s45, s67;
    {
        float4 p0 = *(const float4*)&ws[Q_OFF + f];
        float4 p1 = *(const float4*)&ws[KK_OFF + f];
        s01 = make_float4(p0.x + p1.x, p0.y + p1.y, p0.z + p1.z, p0.w + p1.w);
    }
    {
        float4 p2 = *(const float4*)&ws[V_OFF + f];
        float4 p3 = *(const float4*)&ws[ATTN_OFF + f];
        s23 = make_float4(p2.x + p3.x, p2.y + p3.y, p2.z + p3.z, p2.w + p3.w);
    }
    {
        float4 p4 = *(const float4*)&ws[ATT_OFF + f];
        float4 p5 = *(const float4*)&ws[FFH_OFF + f];
        s45 = make_float4(p4.x + p5.x, p4.y + p5.y, p4.z + p5.z, p4.w + p5.w);
    }
    {
        float4 p6 = *(const float4*)&ws[FFH_OFF + 1048576 + f];
        float4 p7 = *(const float4*)&ws[XSRC_OFF + f];
        s67 = make_float4(p6.x + p7.x, p6.y + p7.y, p6.z + p7.z, p6.w + p7.w);
    }
    float4 sc = *(const float4*)&ws[BN2SC_OFF + e0];
    float4 sh = *(const float4*)&ws[BN2SH_OFF + e0];
    float4 o;
    o.x = gelu_exact(fmaf((s01.x + s23.x) + (s45.x + s67.x), sc.x, sh.x));
    o.y = gelu_exact(fmaf((s01.y + s23.y) + (s45.y + s67.y), sc.y, sh.y));
    o.z = gelu_exact(fmaf((s01.z + s23.z) + (s45.z + s67.z), sc.z, sh.z));
    o.w = gelu_exact(fmaf((s01.w + s23.w) + (s45.w + s67.w), sc.w, sh.w));
    *(float4*)&ws[XSRC_OFF + f] = o;
}

// ---------------- K2: QKV projection via MFMA -> f16 QH(scaled)/KH/VHT (vector stores) ------
__global__ __launch_bounds__(256) void k2_mfma(float* __restrict__ ws) {
    __shared__ unsigned short As[32 * 128];       // 8KB
    __shared__ unsigned short Bs[128 * 128];      // 32KB
    __shared__ float ys[32][132];                 // 16.9KB
    const int t = threadIdx.x;
    const int rt = blockIdx.x, mat = blockIdx.y;
    const int wave = t >> 6, lane = t & 63;

    const char* bg = (const char*)((const unsigned short*)(ws + WQKV_BF_OFF) + mat * 16384);
    #pragma unroll
    for (int c8 = 0; c8 < 8; ++c8) {
        int off = c8 * 4096 + wave * 1024;
        __builtin_amdgcn_global_load_lds(
            (const __attribute__((address_space(1))) unsigned int*)(bg + off + lane * 16),
            (__attribute__((address_space(3))) unsigned int*)(&Bs[off >> 1]), 16, 0, 0);
    }
    const int bs0 = rt * 32;
    const int sl0 = bs0 & 1023;
    for (int i = t; i < 1024; i += 256) {
        int row = i >> 5, d0 = (i & 31) << 2;
        float4 xvv = *(const float4*)&ws[XSRC_OFF + (size_t)(bs0 + row) * EE + d0];
        float4 pv = *(const float4*)&ws[PE_OFF + (size_t)(sl0 + row) * EE + d0];
        us4 o;
        o[0] = f2bf(xvv.x + pv.x); o[1] = f2bf(xvv.y + pv.y);
        o[2] = f2bf(xvv.z + pv.z); o[3] = f2bf(xvv.w + pv.w);
        int slot = (d0 >> 3) ^ (row & 7);
        *(us4*)&As[(row << 7) + (slot << 3) + (d0 & 7)] = o;
    }
    __syncthreads();

    const int wr = wave >> 1, wc = wave & 1;
    const int lrow = lane & 15, lq = lane >> 4;
    f32x4 acc[4];
    #pragma unroll
    for (int i = 0; i < 4; i++) acc[i] = (f32x4){0.f, 0.f, 0.f, 0.f};

    #pragma unroll
    for (int ksname = 0; ksname < 4; ++ksname) {
        int G = (ksname << 2) + lq;
        int arow = (wr << 4) + lrow;
        short8 a = *(const short8*)&As[(arow << 7) + ((G ^ (arow & 7)) << 3)];
        #pragma unroll
        for (int nf = 0; nf < 4; ++nf) {
            int e = (wc << 6) + (nf << 4) + lrow;
            short8 bf = *(const short8*)&Bs[((G >> 3) << 13) + (e << 6) + (((G & 7) ^ (e & 7)) << 3)];
            acc[nf] = __builtin_amdgcn_mfma_f32_16x16x32_bf16(a, bf, acc[nf], 0, 0, 0);
        }
    }

    // C-frag -> LDS (fp32) for vectorized transposed stores
    #pragma unroll
    for (int nf = 0; nf < 4; ++nf) {
        int e = (wc << 6) + (nf << 4) + lrow;
        #pragma unroll
        for (int r = 0; r < 4; ++r)
            ys[(wr << 4) + (lq << 2) + r][e] = acc[nf][r];
    }
    __syncthreads();

    const int b = bs0 >> 10;
    if (mat <= 1) {
        int row = t >> 3, h8 = t & 7;
        float scl = (mat == 0) ? 0.08838834764831845f : 1.0f;
        f16_t* dst = (f16_t*)(ws + (mat == 0 ? Q_OFF : KK_OFF))
                   + (((size_t)(b * HH + h8)) * SS + (sl0 + row)) * DHH;
        half8 v0, v1;
        #pragma unroll
        for (int d = 0; d < 8; d++) v0[d] = (f16_t)(ys[row][h8 * 16 + d] * scl);
        #pragma unroll
        for (int d = 0; d < 8; d++) v1[d] = (f16_t)(ys[row][h8 * 16 + 8 + d] * scl);
        *(half8*)&dst[0] = v0;
        *(half8*)&dst[8] = v1;
    } else {
        int c = t & 127, hf = t >> 7;
        int h8 = c >> 4, d2 = c & 15;
        f16_t* dst = (f16_t*)(ws + V_OFF)
                   + (((size_t)(b * HH + h8)) * DHH + d2) * SS + sl0 + hf * 16;
        half8 v0, v1;
        #pragma unroll
        for (int r = 0; r < 8; r++) v0[r] = (f16_t)ys[hf * 16 + r][c];
        #pragma unroll
        for (int r = 0; r < 8; r++) v1[r] = (f16_t)ys[hf * 16 + 8 + r][c];
        *(half8*)&dst[0] = v0;
        *(half8*)&dst[8] = v1;
    }
}

// ---------------- K3: flash softmax attention + fused rel-bias (mfma 16x16x16 f16) ----------
__global__ __launch_bounds__(256) void k3_attn(const float* __restrict__ rel_tab,
                                               float* __restrict__ ws) {
    __shared__ f16_t rtbl4[4][1088];              // 4 shifted copies for aligned b64 reads
    const int bh = blockIdx.x;                    // b*H + h
    const int h = bh & 7, b = bh >> 3;
    const int i0b = blockIdx.y * 64;
    const int t = threadIdx.x;
    for (int id = t; id < 4 * 1088; id += 256) {
        int p = id / 1088; int j = id - p * 1088;
        int u = j + p;
        float v = (u < 1087) ? rel_tab[(i0b + 1086 - u) * HH + h] : 0.f;
        rtbl4[p][j] = (f16_t)v;
    }
    __syncthreads();

    const int w = t >> 6, lane = t & 63;
    const int q = lane & 15, g = lane >> 4;
    const int r = w * 16 + q;
    const int i = i0b + r;

    const f16_t* QH  = (const f16_t*)(ws + Q_OFF)  + (size_t)bh * SS * DHH;
    const f16_t* KH  = (const f16_t*)(ws + KK_OFF) + (size_t)bh * SS * DHH;
    const f16_t* VHT = (const f16_t*)(ws + V_OFF)  + (size_t)bh * DHH * SS;

    half4 qf = *(const half4*)&QH[(size_t)i * DHH + 4 * g];
    f32x4 o = {0.f, 0.f, 0.f, 0.f};
    f32x4 bv = {0.f, 0.f, 0.f, 0.f};
    const f32x4 zf = {0.f, 0.f, 0.f, 0.f};
    float lp = 0.f;
    const int p4 = (63 - r + 4 * g) & 3;          // vb mod 4, lane-constant

    #pragma unroll 4
    for (int jt = 0; jt < 64; ++jt) {
        half4 kf = *(const half4*)&KH[(size_t)(jt * 16 + q) * DHH + 4 * g];
        f32x4 s = __builtin_amdgcn_mfma_f32_16x16x16f16(kf, qf, zf, 0, 0, 0);
        float p0 = __expf(s[0]), p1 = __expf(s[1]), p2 = __expf(s[2]), p3 = __expf(s[3]);
        lp += (p0 + p1) + (p2 + p3);
        half4 pf;
        pf[0] = (f16_t)p0; pf[1] = (f16_t)p1; pf[2] = (f16_t)p2; pf[3] = (f16_t)p3;
        half4 vf = *(const half4*)&VHT[(size_t)q * SS + jt * 16 + 4 * g];
        o = __builtin_amdgcn_mfma_f32_16x16x16f16(vf, pf, o, 0, 0, 0);
        int vb = 63 - r + jt * 16 + 4 * g;
        half4 bfrag = *(const half4*)&rtbl4[p4][vb & ~3];
        bv = __builtin_amdgcn_mfma_f32_16x16x16f16(vf, bfrag, bv, 0, 0, 0);
    }
    lp += __shfl_xor(lp, 16);
    lp += __shfl_xor(lp, 32);
    float inv = 1.f / lp;
    float4 ov = make_float4(fmaf(o[0], inv, bv[0]), fmaf(o[1], inv, bv[1]),
                            fmaf(o[2], inv, bv[2]), fmaf(o[3], inv, bv[3]));
    *(float4*)&ws[ATTN_OFF + ((size_t)(b * SS) + i) * EE + h * DHH + 4 * g] = ov;
}

// ---------------- K4: LN(attn) -> +x_src -> LN1 -> att ----------------
__global__ __launch_bounds__(256) void k4_ln(const float* __restrict__ g_attn, const float* __restrict__ b_attn,
                                             const float* __restrict__ g1, const float* __restrict__ b1,
                                             float* __restrict__ ws) {
    int row = blockIdx.x * 4 + (threadIdx.x >> 6);
    int lane = threadIdx.x & 63;
    int e0 = lane * 2;
    const float* ain = ws + ATTN_OFF + (size_t)row * EE;
    const float* xsr = ws + XSRC_OFF + (size_t)row * EE;
    float2 a = *(const float2*)(ain + e0);
    float mean = wave_sum(a.x + a.y) * (1.f / 128.f);
    float dx = a.x - mean, dy = a.y - mean;
    float var = wave_sum(dx * dx + dy * dy) * (1.f / 128.f);
    float inv = rsqrtf(var + 1e-5f);
    float n0 = dx * inv * g_attn[e0] + b_attn[e0];
    float n1 = dy * inv * g_attn[e0 + 1] + b_attn[e0 + 1];
    float2 xs2 = *(const float2*)(xsr + e0);
    float z0 = xs2.x + n0, z1 = xs2.y + n1;
    float m2 = wave_sum(z0 + z1) * (1.f / 128.f);
    float d0 = z0 - m2, d1 = z1 - m2;
    float v2 = wave_sum(d0 * d0 + d1 * d1) * (1.f / 128.f);
    float inv2 = rsqrtf(v2 + 1e-5f);
    float o0 = d0 * inv2 * g1[e0] + b1[e0];
    float o1 = d1 * inv2 * g1[e0 + 1] + b1[e0 + 1];
    *(float2*)(ws + ATT_OFF + (size_t)row * EE + e0) = make_float2(o0, o1);
}

// ---------------- K5: FF1 via MFMA + bias + relu -> bf16 swizzled FFHB (vector stores) ------
__global__ __launch_bounds__(256) void k5_mfma(const float* __restrict__ b1,
                                               float* __restrict__ ws) {
    __shared__ unsigned short As[32 * 128];
    __shared__ unsigned short Bs[128 * 128];
    __shared__ float ys[32][132];
    const int t = threadIdx.x;
    const int rt = blockIdx.x, nb = blockIdx.y;
    const int wave = t >> 6, lane = t & 63;

    const char* bg = (const char*)((const unsigned short*)(ws + W1FF_BF_OFF) + nb * 16384);
    #pragma unroll
    for (int c8 = 0; c8 < 8; ++c8) {
        int off = c8 * 4096 + wave * 1024;
        __builtin_amdgcn_global_load_lds(
            (const __attribute__((address_space(1))) unsigned int*)(bg + off + lane * 16),
            (__attribute__((address_space(3))) unsigned int*)(&Bs[off >> 1]), 16, 0, 0);
    }
    const int bs0 = rt * 32;
    for (int i = t; i < 1024; i += 256) {
        int row = i >> 5, d0 = (i & 31) << 2;
        float4 xvv = *(const float4*)&ws[ATT_OFF + (size_t)(bs0 + row) * EE + d0];
        us4 o;
        o[0] = f2bf(xvv.x); o[1] = f2bf(xvv.y); o[2] = f2bf(xvv.z); o[3] = f2bf(xvv.w);
        int slot = (d0 >> 3) ^ (row & 7);
        *(us4*)&As[(row << 7) + (slot << 3) + (d0 & 7)] = o;
    }
    __syncthreads();

    const int wr = wave >> 1, wc = wave & 1;
    const int lrow = lane & 15, lq = lane >> 4;
    f32x4 acc[4];
    #pragma unroll
    for (int i = 0; i < 4; i++) acc[i] = (f32x4){0.f, 0.f, 0.f, 0.f};

    #pragma unroll
    for (int ksname = 0; ksname < 4; ++ksname) {
        int G = (ksname << 2) + lq;
        int arow = (wr << 4) + lrow;
        short8 a = *(const short8*)&As[(arow << 7) + ((G ^ (arow & 7)) << 3)];
        #pragma unroll
        for (int nf = 0; nf < 4; ++nf) {
            int e = (wc << 6) + (nf << 4) + lrow;
            short8 bf = *(const short8*)&Bs[((G >> 3) << 13) + (e << 6) + (((G & 7) ^ (e & 7)) << 3)];
            acc[nf] = __builtin_amdgcn_mfma_f32_16x16x32_bf16(a, bf, acc[nf], 0, 0, 0);
        }
    }

    #pragma unroll
    for (int nf = 0; nf < 4; ++nf) {
        int col = (wc << 6) + (nf << 4) + lrow;
        float bias = b1[(nb << 7) + col];
        #pragma unroll
        for (int r = 0; r < 4; ++r)
            ys[(wr << 4) + (lq << 2) + r][col] = fmaxf(acc[nf][r] + bias, 0.f);
    }
    __syncthreads();

    unsigned short* ffhb = (unsigned short*)(ws + FFH_OFF);
    #pragma unroll
    for (int kk = 0; kk < 2; ++kk) {
        int id = t + kk * 256;
        int ssr = id >> 4, fg = id & 15;
        float4 v0 = *(const float4*)&ys[ssr][fg * 8];
        float4 v1 = *(const float4*)&ys[ssr][fg * 8 + 4];
        ushort8 ov;
        ov[0] = f2bf(v0.x); ov[1] = f2bf(v0.y); ov[2] = f2bf(v0.z); ov[3] = f2bf(v0.w);
        ov[4] = f2bf(v1.x); ov[5] = f2bf(v1.y); ov[6] = f2bf(v1.z); ov[7] = f2bf(v1.w);
        int kb = (nb << 1) + (fg >> 3);
        int slot = (fg & 7) ^ (ssr & 7);
        *(ushort8*)&ffhb[(((size_t)(rt * 8 + kb) * 32 + ssr) << 6) + (slot << 3)] = ov;
    }
}

// ---------------- K6: FF2 via MFMA + bias + residual + LN2 + transposed store ----------------
__global__ __launch_bounds__(256) void k6_mfma(const float* __restrict__ b2,
                                               const float* __restrict__ g2, const float* __restrict__ bb2,
                                               float* __restrict__ ws, float* __restrict__ out) {
    __shared__ unsigned short Ab[2][2048];    // 2x4KB
    __shared__ unsigned short Bb[2][8192];    // 2x16KB
    __shared__ float y[32][132];              // 16.9KB
    const int t = threadIdx.x;
    const int wave = t >> 6, lane = t & 63;
    const int rt = blockIdx.x;

    const char* ag = (const char*)((const unsigned short*)(ws + FFH_OFF) + (size_t)rt * 16384);
    const char* bgc = (const char*)(ws + W2FF_BF_OFF);

    auto stage = [&](int kb, int buf) {
        __builtin_amdgcn_global_load_lds(
            (const __attribute__((address_space(1))) unsigned int*)(ag + kb * 4096 + t * 16),
            (__attribute__((address_space(3))) unsigned int*)(&Ab[buf][(t * 16) >> 1]), 16, 0, 0);
        const char* g = bgc + kb * 16384;
        #pragma unroll
        for (int c4 = 0; c4 < 4; ++c4) {
            int off = c4 * 4096 + wave * 1024;
            __builtin_amdgcn_global_load_lds(
                (const __attribute__((address_space(1))) unsigned int*)(g + off + lane * 16),
                (__attribute__((address_space(3))) unsigned int*)(&Bb[buf][off >> 1]), 16, 0, 0);
        }
    };

    const int wr = wave >> 1, wc = wave & 1;
    const int lrow = lane & 15, lq = lane >> 4;
    f32x4 acc[4];
    #pragma unroll
    for (int i = 0; i < 4; i++) acc[i] = (f32x4){0.f, 0.f, 0.f, 0.f};

    stage(0, 0);
    __syncthreads();
    for (int kb = 0; kb < 8; ++kb) {
        int cur = kb & 1;
        if (kb < 7) stage(kb + 1, cur ^ 1);
        #pragma unroll
        for (int ksname = 0; ksname < 2; ++ksname) {
            int G = (ksname << 2) + lq;
            int arow = (wr << 4) + lrow;
            short8 a = *(const short8*)&Ab[cur][(arow << 6) + ((G ^ (arow & 7)) << 3)];
            #pragma unroll
            for (int nf = 0; nf < 4; ++nf) {
                int e = (wc << 6) + (nf << 4) + lrow;
                short8 bf = *(const short8*)&Bb[cur][(e << 6) + ((G ^ (e & 7)) << 3)];
                acc[nf] = __builtin_amdgcn_mfma_f32_16x16x32_bf16(a, bf, acc[nf], 0, 0, 0);
            }
        }
        __syncthreads();
    }

    const int bs0 = rt * 32;
    #pragma unroll
    for (int nf = 0; nf < 4; ++nf) {
        int e = (wc << 6) + (nf << 4) + lrow;
        float bvv = b2[e];
        #pragma unroll
        for (int r = 0; r < 4; ++r) {
            int row = (wr << 4) + (lq << 2) + r;
            y[row][e] = acc[nf][r] + bvv + ws[ATT_OFF + (size_t)(bs0 + row) * EE + e];
        }
    }
    __syncthreads();
    int e0 = lane * 2;
    for (int rr = 0; rr < 8; rr++) {
        int row = wave * 8 + rr;
        float z0 = y[row][e0], z1 = y[row][e0 + 1];
        float mean = wave_sum(z0 + z1) * (1.f / 128.f);
        float d0 = z0 - mean, d1 = z1 - mean;
        float var = wave_sum(d0 * d0 + d1 * d1) * (1.f / 128.f);
        float inv = rsqrtf(var + 1e-5f);
        y[row][e0]     = d0 * inv * g2[e0] + bb2[e0];
        y[row][e0 + 1] = d1 * inv * g2[e0 + 1] + bb2[e0 + 1];
    }
    __syncthreads();
    int b = bs0 >> 10, s0 = bs0 & 1023;
    int sl = t & 31, eg = t >> 5;
    #pragma unroll
    for (int rep = 0; rep < 16; rep++) {
        int e = eg * 16 + rep;
        out[(size_t)b * EE * SS + (size_t)e * SS + s0 + sl] = y[sl][e];
    }
}

extern "C" void kernel_launch(void* const* d_in, const int* in_sizes, int n_in,
                              void* d_out, int out_size, void* d_ws, size_t ws_size,
                              hipStream_t stream) {
    const float* x        = (const float*)d_in[0];
    const float* conv1_w  = (const float*)d_in[1];
    const float* conv1_b  = (const float*)d_in[2];
    const float* bn1_g    = (const float*)d_in[3];
    const float* bn1_b    = (const float*)d_in[4];
    const float* bn1_m    = (const float*)d_in[5];
    const float* bn1_v    = (const float*)d_in[6];
    const float* conv2_w  = (const float*)d_in[7];
    const float* conv2_b  = (const float*)d_in[8];
    const float* bn2_g    = (const float*)d_in[9];
    const float* bn2_b    = (const float*)d_in[10];
    const float* bn2_m    = (const float*)d_in[11];
    const float* bn2_v    = (const float*)d_in[12];
    const float* wq       = (const float*)d_in[13];
    const float* wk       = (const float*)d_in[14];
    const float* wv       = (const float*)d_in[15];
    const float* rel_tab  = (const float*)d_in[16];
    const float* ln_attn_g = (const float*)d_in[17];
    const float* ln_attn_b = (const float*)d_in[18];
    const float* ln1_g    = (const float*)d_in[19];
    const float* ln1_b    = (const float*)d_in[20];
    const float* ln2_g    = (const float*)d_in[21];
    const float* ln2_b    = (const float*)d_in[22];
    const float* ff_w1    = (const float*)d_in[23];
    const float* ff_b1    = (const float*)d_in[24];
    const float* ff_w2    = (const float*)d_in[25];
    const float* ff_b2    = (const float*)d_in[26];

    float* ws  = (float*)d_ws;
    float* out = (float*)d_out;

    hipLaunchKernelGGL(k0_all, dim3(1116), dim3(256), 0, stream,
                       conv1_w, conv1_b, bn1_g, bn1_b, bn1_m, bn1_v,
                       conv2_w, conv2_b, bn2_g, bn2_b, bn2_m, bn2_v,
                       wq, wk, wv, ff_w1, ff_w2, ws);
    hipLaunchKernelGGL(k1_mfma, dim3(128, 8), dim3(256), 0, stream, x, ws);
    hipLaunchKernelGGL(k1b_combine, dim3(1024), dim3(256), 0, stream, ws);
    hipLaunchKernelGGL(k2_mfma, dim3(256, 3), dim3(256), 0, stream, ws);
    hipLaunchKernelGGL(k3_attn, dim3(BB * HH, SS / 64), dim3(256), 0, stream, rel_tab, ws);
    hipLaunchKernelGGL(k4_ln, dim3(BB * SS / 4), dim3(256), 0, stream, ln_attn_g, ln_attn_b, ln1_g, ln1_b, ws);
    hipLaunchKernelGGL(k5_mfma, dim3(256, 4), dim3(256), 0, stream, ff_b1, ws);
    hipLaunchKernelGGL(k6_mfma, dim3(256), dim3(256), 0, stream, ff_b2, ln2_g, ln2_b, ws, out);
}

// Round 17
// 169.339 us; speedup vs baseline: 1.0759x; 1.0759x over previous
//
#include <hip/hip_runtime.h>
#include <math.h>

// Problem constants
#define BB    8
#define CIN   16
#define SS    1024
#define EE    128
#define HH    8
#define DHH   16
#define O1    512      // E*4
#define DFFN  512
#define K2TOT 8192     // O1*CIN

// Workspace layout (float offsets)
#define PE_OFF    0            // 131072  (S*E)
#define BN1SC_OFF 131072       // 512 (unused; kept)
#define BN1SH_OFF 131584       // 512
#define BN2SC_OFF 132096       // 128
#define BN2SH_OFF 132224       // 128
#define W1P_OFF   133120       // bf16 folded conv1 taps [512 o][8 u]
#define WQKV_BF_OFF 135168     // bf16 wq|wk|wv, each 16384 elems
#define W1FF_BF_OFF 159744     // bf16 ff_w1 [4nb][2kb][128][64]
#define W2FF_BF_OFF 192512     // bf16 ff_w2 [8kb][128][64]
#define XSRC_OFF  262144       // 1048576 (B*S*E) fp32
#define Q_OFF     1310720      // QH: f16 scaled        | k1 partial P0
#define KK_OFF    2359296      // KH                    | k1 partial P1
#define V_OFF     3407872      // VHT                   | k1 partial P2
#define ATTN_OFF  4456448      // (B,S,E) attn out      | k1 partial P3
#define ATT_OFF   5505024      // (B,S,E) post-LN1 (written by k5 nb==0)
#define FFH_OFF   6553600      // k5 bf16 out (2M floats region)
#define W2CONV_BF_OFF 8650752  // bf16 conv2_w (straight k=o*16+c), [128kb][128e][64]
// end: 9175040 floats = 36.7 MB
// NOTE: k1 writes 4 fp32 partials into Q/K/V/ATTN regions; k1b combines into
// XSRC before k2/k3 overwrite those regions. Launch order guarantees safety.

typedef __attribute__((ext_vector_type(8))) short short8;
typedef __attribute__((ext_vector_type(8))) unsigned short ushort8;
typedef __attribute__((ext_vector_type(4))) unsigned short us4;
typedef __attribute__((ext_vector_type(4))) float f32x4;
typedef _Float16 f16_t;
typedef __attribute__((ext_vector_type(4))) _Float16 half4;
typedef __attribute__((ext_vector_type(8))) _Float16 half8;

__device__ __forceinline__ float wave_sum(float v) {
    #pragma unroll
    for (int o = 32; o > 0; o >>= 1) v += __shfl_xor(v, o);
    return v;
}

__device__ __forceinline__ float gelu_exact(float x) {
    return 0.5f * x * (1.0f + erff(x * 0.7071067811865476f));
}

// x - x/(1+exp(2*inner)), constants pre-doubled
__device__ __forceinline__ float gelu_tanh(float x) {
    float x2 = x * x;
    float y = x * fmaf(0.0713548162f, x2, 1.5957691216f);
    float E = __expf(y);
    float r = __builtin_amdgcn_rcpf(E + 1.0f);
    return fmaf(-x, r, x);
}

__device__ __forceinline__ unsigned short f2bf(float f) {   // RNE fp32->bf16
    unsigned int u = __float_as_uint(f);
    unsigned int r = u + 0x7FFFu + ((u >> 16) & 1u);
    return (unsigned short)(r >> 16);
}

__device__ __forceinline__ float bf2f(unsigned short u) {
    return __uint_as_float(((unsigned int)u) << 16);
}

// generic weight cast fp32 -> bf16, chunk-major, pre-swizzled (m173 pattern)
__device__ __forceinline__ void castw_body(const float* __restrict__ src,
                                           unsigned short* __restrict__ dst, int K, int tid) {
    int g = tid & 7, e = (tid >> 3) & 127, rest = tid >> 10;
    int KB = K >> 6;
    int kb = rest % KB, nb = rest / KB;
    int col = nb * 128 + e;
    const float* s = src + (size_t)col * K + kb * 64 + ((g ^ (e & 7)) << 3);
    ushort8 v;
    #pragma unroll
    for (int j = 0; j < 8; j++) v[j] = f2bf(s[j]);
    *(ushort8*)&dst[(size_t)tid << 3] = v;
}

// ---------------- K0: ALL setup jobs fused (independent; branch on blockIdx) ----------------
__global__ __launch_bounds__(256) void k0_all(const float* __restrict__ conv1_w,
                                              const float* __restrict__ conv1_b,
                                              const float* __restrict__ bn1_g,
                                              const float* __restrict__ bn1_b,
                                              const float* __restrict__ bn1_m,
                                              const float* __restrict__ bn1_v,
                                              const float* __restrict__ conv2_w,
                                              const float* __restrict__ conv2_b,
                                              const float* __restrict__ bn2_g,
                                              const float* __restrict__ bn2_b,
                                              const float* __restrict__ bn2_m,
                                              const float* __restrict__ bn2_v,
                                              const float* __restrict__ wq,
                                              const float* __restrict__ wk,
                                              const float* __restrict__ wv,
                                              const float* __restrict__ ff_w1,
                                              const float* __restrict__ ff_w2,
                                              float* __restrict__ ws) {
    int bid = blockIdx.x, t = threadIdx.x;
    if (bid < 512) {                       // PE table
        int idx = bid * 256 + t;
        int s = idx >> 7, e = idx & 127;
        int i = e >> 1;
        float freq = expf((float)(2 * i) * (-9.210340371976184f / 128.0f));
        float ang = (float)s * freq * 0.125f;
        ws[PE_OFF + idx] = (e & 1) ? cosf(ang) : sinf(ang);
    } else if (bid < 515) {                // BN fold
        int u = (bid - 512) * 256 + t;
        if (u < 512) {
            float sc = bn1_g[u] * rsqrtf(bn1_v[u] + 1e-5f);
            ws[BN1SC_OFF + u] = sc;
            ws[BN1SH_OFF + u] = (conv1_b[u] - bn1_m[u]) * sc + bn1_b[u];
        } else if (u < 640) {
            int e = u - 512;
            float sc = bn2_g[e] * rsqrtf(bn2_v[e] + 1e-5f);
            ws[BN2SC_OFF + e] = sc;
            ws[BN2SH_OFF + e] = (conv2_b[e] - bn2_m[e]) * sc + bn2_b[e];
        }
    } else if (bid < 1027) {               // conv2_w cast (straight layout)
        castw_body(conv2_w, (unsigned short*)(ws + W2CONV_BF_OFF), 8192, (bid - 515) * 256 + t);
    } else if (bid < 1035) {
        castw_body(wq, (unsigned short*)(ws + WQKV_BF_OFF), 128, (bid - 1027) * 256 + t);
    } else if (bid < 1043) {
        castw_body(wk, (unsigned short*)(ws + WQKV_BF_OFF) + 16384, 128, (bid - 1035) * 256 + t);
    } else if (bid < 1051) {
        castw_body(wv, (unsigned short*)(ws + WQKV_BF_OFF) + 32768, 128, (bid - 1043) * 256 + t);
    } else if (bid < 1083) {
        castw_body(ff_w1, (unsigned short*)(ws + W1FF_BF_OFF), 128, (bid - 1051) * 256 + t);
    } else if (bid < 1115) {
        castw_body(ff_w2, (unsigned short*)(ws + W2FF_BF_OFF), 512, (bid - 1083) * 256 + t);
    } else {                               // folded bf16 conv1 taps: w1p[o][u] = w1[o][u]*sc1[o]
        unsigned short* w1p = (unsigned short*)(ws + W1P_OFF);
        for (int id = t; id < 4096; id += 256) {
            int o = id >> 3, u = id & 7;
            float sc = bn1_g[o] * rsqrtf(bn1_v[o] + 1e-5f);
            float v = (u < 7) ? conv1_w[o * 7 + u] * sc : 0.f;
            w1p[id] = f2bf(v);
        }
    }
}

// ---------------- K1: fused conv1+bn1+gelu -> conv2 (bf16 MFMA), BARRIER-FREE (R9) ----------
// BM=64, 4 waves; wave w owns output rows [w*16, w*16+16) x ALL 128 e.
// A-fragment computed DIRECTLY in registers in MFMA layout (lane-constant c-set; 56 x-taps
// hoisted). B (w2 bf16, pre-swizzled) streamed global->regs 8+8. No A-LDS, no barriers.
// K-split x4 -> grid (128,4); fp32 partials to Q/K/V/ATTN regions. Best measured: 69.6us.
__global__ __launch_bounds__(256) void k1_mfma(const float* __restrict__ x,
                                               float* __restrict__ ws) {
    __shared__ float xt[CIN][72];                 // 4.5KB: x[b,c, s0-3 .. s0+66]
    __shared__ unsigned short w1ps[128 * 8];      // 2KB (this K-quarter's 128 o-rows)
    __shared__ float sh1s[128];                   // 0.5KB

    const int t = threadIdx.x;
    const int wave = t >> 6, lane = t & 63;
    const int row0 = blockIdx.x * 64;
    const int ksplit = blockIdx.y;                // K-quarter
    const int b = row0 >> 10, s0 = row0 & 1023;
    const int obase = ksplit * 128;

    for (int i = t; i < CIN * 70; i += 256) {
        int c = i / 70, j = i % 70;
        int gs = s0 + j - 3;
        xt[c][j] = (gs >= 0 && gs < SS) ? x[(b * CIN + c) * SS + gs] : 0.f;
    }
    if (t < 128) {
        *(ushort8*)&w1ps[t << 3] =
            ((const ushort8*)((const unsigned short*)(ws + W1P_OFF)))[obase + t];
        sh1s[t] = ws[BN1SH_OFF + obase + t];
    }
    __syncthreads();                              // the ONLY barrier

    const int lrow = lane & 15, lq = lane >> 4;
    const int srow_local = (wave << 4) + lrow;    // 0..63
    const int cbase = (lq & 1) << 3;

    // hoist the 56 x-taps (8 c x 7 u) for this lane's fixed row
    float xv[56];
    #pragma unroll
    for (int c8 = 0; c8 < 8; ++c8)
        #pragma unroll
        for (int u = 0; u < 7; ++u)
            xv[c8 * 7 + u] = xt[cbase + c8][srow_local + u];

    // lane-constant B byte offsets within a 16KB chunk: i = ks2*8+nf
    int boff[16];
    #pragma unroll
    for (int ks2 = 0; ks2 < 2; ++ks2) {
        int G = (ks2 << 2) + lq;
        #pragma unroll
        for (int nf = 0; nf < 8; ++nf) {
            int e = (nf << 4) + lrow;
            boff[ks2 * 8 + nf] = (e << 7) + ((G ^ (e & 7)) << 4);
        }
    }

    const char* w2g = (const char*)(ws + W2CONV_BF_OFF);
    const int olq = lq >> 1;

    auto computeA = [&](int kbl, int ks2) -> short8 {
        int ol = (kbl << 2) + (ks2 << 1) + olq;
        ushort8 w8 = *(const ushort8*)&w1ps[ol << 3];
        float w0 = bf2f(w8[0]), w1_ = bf2f(w8[1]), w2_ = bf2f(w8[2]), w3 = bf2f(w8[3]);
        float w4 = bf2f(w8[4]), w5 = bf2f(w8[5]), w6 = bf2f(w8[6]);
        float sh = sh1s[ol];
        short8 a;
        #pragma unroll
        for (int j = 0; j < 8; ++j) {
            float p = xv[j*7]   * w0 + xv[j*7+1] * w1_ + xv[j*7+2] * w2_ + xv[j*7+3] * w3
                    + xv[j*7+4] * w4 + xv[j*7+5] * w5 + xv[j*7+6] * w6;
            a[j] = (short)f2bf(gelu_tanh(p + sh));
        }
        return a;
    };

    f32x4 acc[8];
    #pragma unroll
    for (int i = 0; i < 8; ++i) acc[i] = (f32x4){0.f, 0.f, 0.f, 0.f};

    #pragma unroll 1
    for (int kbl = 0; kbl < 32; ++kbl) {
        const char* g = w2g + ((size_t)((ksplit << 5) + kbl) << 14);
        short8 bA_[8];
        #pragma unroll
        for (int i = 0; i < 8; ++i) bA_[i] = *(const short8*)(g + boff[i]);
        short8 a0 = computeA(kbl, 0);             // VALU overlaps the loads above
        short8 bB_[8];
        #pragma unroll
        for (int i = 0; i < 8; ++i) bB_[i] = *(const short8*)(g + boff[8 + i]);
        #pragma unroll
        for (int nf = 0; nf < 8; ++nf)
            acc[nf] = __builtin_amdgcn_mfma_f32_16x16x32_bf16(a0, bA_[nf], acc[nf], 0, 0, 0);
        short8 a1 = computeA(kbl, 1);
        #pragma unroll
        for (int nf = 0; nf < 8; ++nf)
            acc[nf] = __builtin_amdgcn_mfma_f32_16x16x32_bf16(a1, bB_[nf], acc[nf], 0, 0, 0);
    }

    // store fp32 partial (no bn2/gelu yet) into Q/K/V/ATTN region for this split
    float* P = ws + Q_OFF + (size_t)ksplit * 1048576;
    #pragma unroll
    for (int nf = 0; nf < 8; ++nf) {
        int e = (nf << 4) + lrow;
        #pragma unroll
        for (int r = 0; r < 4; ++r) {
            int srow = s0 + (wave << 4) + (lq << 2) + r;
            P[(((size_t)(b * SS + srow)) << 7) + e] = acc[nf][r];
        }
    }
}

// ---------------- K1b: combine 4 partials + bn2 + exact gelu -> x_src ----------------
__global__ __launch_bounds__(256) void k1b_combine(float* __restrict__ ws) {
    int f = (blockIdx.x * 256 + threadIdx.x) * 4;   // 1M elems
    int e0 = f & 127;
    float4 p0 = *(const float4*)&ws[Q_OFF + f];
    float4 p1 = *(const float4*)&ws[KK_OFF + f];
    float4 p2 = *(const float4*)&ws[V_OFF + f];
    float4 p3 = *(const float4*)&ws[ATTN_OFF + f];
    float4 sc = *(const float4*)&ws[BN2SC_OFF + e0];
    float4 sh = *(const float4*)&ws[BN2SH_OFF + e0];
    float4 o;
    o.x = gelu_exact(fmaf((p0.x + p1.x) + (p2.x + p3.x), sc.x, sh.x));
    o.y = gelu_exact(fmaf((p0.y + p1.y) + (p2.y + p3.y), sc.y, sh.y));
    o.z = gelu_exact(fmaf((p0.z + p1.z) + (p2.z + p3.z), sc.z, sh.z));
    o.w = gelu_exact(fmaf((p0.w + p1.w) + (p2.w + p3.w), sc.w, sh.w));
    *(float4*)&ws[XSRC_OFF + f] = o;
}

// ---------------- K2: QKV projection via MFMA -> f16 QH(scaled)/KH/VHT (vector stores) ------
__global__ __launch_bounds__(256) void k2_mfma(float* __restrict__ ws) {
    __shared__ unsigned short As[32 * 128];       // 8KB
    __shared__ unsigned short Bs[128 * 128];      // 32KB
    __shared__ float ys[32][132];                 // 16.9KB
    const int t = threadIdx.x;
    const int rt = blockIdx.x, mat = blockIdx.y;
    const int wave = t >> 6, lane = t & 63;

    const char* bg = (const char*)((const unsigned short*)(ws + WQKV_BF_OFF) + mat * 16384);
    #pragma unroll
    for (int c8 = 0; c8 < 8; ++c8) {
        int off = c8 * 4096 + wave * 1024;
        __builtin_amdgcn_global_load_lds(
            (const __attribute__((address_space(1))) unsigned int*)(bg + off + lane * 16),
            (__attribute__((address_space(3))) unsigned int*)(&Bs[off >> 1]), 16, 0, 0);
    }
    const int bs0 = rt * 32;
    const int sl0 = bs0 & 1023;
    for (int i = t; i < 1024; i += 256) {
        int row = i >> 5, d0 = (i & 31) << 2;
        float4 xvv = *(const float4*)&ws[XSRC_OFF + (size_t)(bs0 + row) * EE + d0];
        float4 pv = *(const float4*)&ws[PE_OFF + (size_t)(sl0 + row) * EE + d0];
        us4 o;
        o[0] = f2bf(xvv.x + pv.x); o[1] = f2bf(xvv.y + pv.y);
        o[2] = f2bf(xvv.z + pv.z); o[3] = f2bf(xvv.w + pv.w);
        int slot = (d0 >> 3) ^ (row & 7);
        *(us4*)&As[(row << 7) + (slot << 3) + (d0 & 7)] = o;
    }
    __syncthreads();

    const int wr = wave >> 1, wc = wave & 1;
    const int lrow = lane & 15, lq = lane >> 4;
    f32x4 acc[4];
    #pragma unroll
    for (int i = 0; i < 4; i++) acc[i] = (f32x4){0.f, 0.f, 0.f, 0.f};

    #pragma unroll
    for (int ksname = 0; ksname < 4; ++ksname) {
        int G = (ksname << 2) + lq;
        int arow = (wr << 4) + lrow;
        short8 a = *(const short8*)&As[(arow << 7) + ((G ^ (arow & 7)) << 3)];
        #pragma unroll
        for (int nf = 0; nf < 4; ++nf) {
            int e = (wc << 6) + (nf << 4) + lrow;
            short8 bf = *(const short8*)&Bs[((G >> 3) << 13) + (e << 6) + (((G & 7) ^ (e & 7)) << 3)];
            acc[nf] = __builtin_amdgcn_mfma_f32_16x16x32_bf16(a, bf, acc[nf], 0, 0, 0);
        }
    }

    // C-frag -> LDS (fp32) for vectorized transposed stores
    #pragma unroll
    for (int nf = 0; nf < 4; ++nf) {
        int e = (wc << 6) + (nf << 4) + lrow;
        #pragma unroll
        for (int r = 0; r < 4; ++r)
            ys[(wr << 4) + (lq << 2) + r][e] = acc[nf][r];
    }
    __syncthreads();

    const int b = bs0 >> 10;
    if (mat <= 1) {
        int row = t >> 3, h8 = t & 7;
        float scl = (mat == 0) ? 0.08838834764831845f : 1.0f;
        f16_t* dst = (f16_t*)(ws + (mat == 0 ? Q_OFF : KK_OFF))
                   + (((size_t)(b * HH + h8)) * SS + (sl0 + row)) * DHH;
        half8 v0, v1;
        #pragma unroll
        for (int d = 0; d < 8; d++) v0[d] = (f16_t)(ys[row][h8 * 16 + d] * scl);
        #pragma unroll
        for (int d = 0; d < 8; d++) v1[d] = (f16_t)(ys[row][h8 * 16 + 8 + d] * scl);
        *(half8*)&dst[0] = v0;
        *(half8*)&dst[8] = v1;
    } else {
        int c = t & 127, hf = t >> 7;
        int h8 = c >> 4, d2 = c & 15;
        f16_t* dst = (f16_t*)(ws + V_OFF)
                   + (((size_t)(b * HH + h8)) * DHH + d2) * SS + sl0 + hf * 16;
        half8 v0, v1;
        #pragma unroll
        for (int r = 0; r < 8; r++) v0[r] = (f16_t)ys[hf * 16 + r][c];
        #pragma unroll
        for (int r = 0; r < 8; r++) v1[r] = (f16_t)ys[hf * 16 + 8 + r][c];
        *(half8*)&dst[0] = v0;
        *(half8*)&dst[8] = v1;
    }
}

// ---------------- K3: flash softmax attention + fused rel-bias (mfma 16x16x16 f16) ----------
__global__ __launch_bounds__(256) void k3_attn(const float* __restrict__ rel_tab,
                                               float* __restrict__ ws) {
    __shared__ f16_t rtbl4[4][1088];              // 4 shifted copies for aligned b64 reads
    const int bh = blockIdx.x;                    // b*H + h
    const int h = bh & 7, b = bh >> 3;
    const int i0b = blockIdx.y * 64;
    const int t = threadIdx.x;
    for (int id = t; id < 4 * 1088; id += 256) {
        int p = id / 1088; int j = id - p * 1088;
        int u = j + p;
        float v = (u < 1087) ? rel_tab[(i0b + 1086 - u) * HH + h] : 0.f;
        rtbl4[p][j] = (f16_t)v;
    }
    __syncthreads();

    const int w = t >> 6, lane = t & 63;
    const int q = lane & 15, g = lane >> 4;
    const int r = w * 16 + q;
    const int i = i0b + r;

    const f16_t* QH  = (const f16_t*)(ws + Q_OFF)  + (size_t)bh * SS * DHH;
    const f16_t* KH  = (const f16_t*)(ws + KK_OFF) + (size_t)bh * SS * DHH;
    const f16_t* VHT = (const f16_t*)(ws + V_OFF)  + (size_t)bh * DHH * SS;

    half4 qf = *(const half4*)&QH[(size_t)i * DHH + 4 * g];
    f32x4 o = {0.f, 0.f, 0.f, 0.f};
    f32x4 bv = {0.f, 0.f, 0.f, 0.f};
    const f32x4 zf = {0.f, 0.f, 0.f, 0.f};
    float lp = 0.f;
    const int p4 = (63 - r + 4 * g) & 3;          // vb mod 4, lane-constant

    #pragma unroll 4
    for (int jt = 0; jt < 64; ++jt) {
        half4 kf = *(const half4*)&KH[(size_t)(jt * 16 + q) * DHH + 4 * g];
        f32x4 s = __builtin_amdgcn_mfma_f32_16x16x16f16(kf, qf, zf, 0, 0, 0);
        float p0 = __expf(s[0]), p1 = __expf(s[1]), p2 = __expf(s[2]), p3 = __expf(s[3]);
        lp += (p0 + p1) + (p2 + p3);
        half4 pf;
        pf[0] = (f16_t)p0; pf[1] = (f16_t)p1; pf[2] = (f16_t)p2; pf[3] = (f16_t)p3;
        half4 vf = *(const half4*)&VHT[(size_t)q * SS + jt * 16 + 4 * g];
        o = __builtin_amdgcn_mfma_f32_16x16x16f16(vf, pf, o, 0, 0, 0);
        int vb = 63 - r + jt * 16 + 4 * g;
        half4 bfrag = *(const half4*)&rtbl4[p4][vb & ~3];
        bv = __builtin_amdgcn_mfma_f32_16x16x16f16(vf, bfrag, bv, 0, 0, 0);
    }
    lp += __shfl_xor(lp, 16);
    lp += __shfl_xor(lp, 32);
    float inv = 1.f / lp;
    float4 ov = make_float4(fmaf(o[0], inv, bv[0]), fmaf(o[1], inv, bv[1]),
                            fmaf(o[2], inv, bv[2]), fmaf(o[3], inv, bv[3]));
    *(float4*)&ws[ATTN_OFF + ((size_t)(b * SS) + i) * EE + h * DHH + 4 * g] = ov;
}

// ---------------- K5: FUSED LN(attn)+residual+LN1 -> FF1 MFMA + bias + relu ----------------
// k4 folded in: each block recomputes the double-LN for its 32 rows (4x redundant across nb,
// cheap); nb==0 blocks also store fp32 ATT for k6's residual (k6 launches after k5).
__global__ __launch_bounds__(256) void k5_fused(const float* __restrict__ g_attn,
                                                const float* __restrict__ b_attn,
                                                const float* __restrict__ g1,
                                                const float* __restrict__ b1,
                                                const float* __restrict__ ff_b1,
                                                float* __restrict__ ws) {
    __shared__ unsigned short As[32 * 128];
    __shared__ unsigned short Bs[128 * 128];
    __shared__ float ys[32][132];
    const int t = threadIdx.x;
    const int rt = blockIdx.x, nb = blockIdx.y;
    const int wave = t >> 6, lane = t & 63;

    const char* bg = (const char*)((const unsigned short*)(ws + W1FF_BF_OFF) + nb * 16384);
    #pragma unroll
    for (int c8 = 0; c8 < 8; ++c8) {
        int off = c8 * 4096 + wave * 1024;
        __builtin_amdgcn_global_load_lds(
            (const __attribute__((address_space(1))) unsigned int*)(bg + off + lane * 16),
            (__attribute__((address_space(3))) unsigned int*)(&Bs[off >> 1]), 16, 0, 0);
    }

    // fused A-stage: LN(attn) -> +xsrc -> LN1 -> bf16 swizzled As (+ ATT store on nb==0)
    const int bs0 = rt * 32;
    const int e0 = lane * 2;
    const float ga0 = g_attn[e0], ga1 = g_attn[e0 + 1];
    const float ba0 = b_attn[e0], ba1 = b_attn[e0 + 1];
    const float g10 = g1[e0], g11 = g1[e0 + 1];
    const float b10 = b1[e0], b11 = b1[e0 + 1];
    #pragma unroll 1
    for (int rr = 0; rr < 8; ++rr) {
        int row = wave * 8 + rr;                  // 0..31
        int grow = bs0 + row;
        float2 a2 = *(const float2*)&ws[ATTN_OFF + (size_t)grow * EE + e0];
        float mean = wave_sum(a2.x + a2.y) * (1.f / 128.f);
        float dx = a2.x - mean, dy = a2.y - mean;
        float var = wave_sum(dx * dx + dy * dy) * (1.f / 128.f);
        float inv = rsqrtf(var + 1e-5f);
        float n0 = dx * inv * ga0 + ba0;
        float n1 = dy * inv * ga1 + ba1;
        float2 xs2 = *(const float2*)&ws[XSRC_OFF + (size_t)grow * EE + e0];
        float z0 = xs2.x + n0, z1 = xs2.y + n1;
        float m2 = wave_sum(z0 + z1) * (1.f / 128.f);
        float d0 = z0 - m2, d1 = z1 - m2;
        float v2 = wave_sum(d0 * d0 + d1 * d1) * (1.f / 128.f);
        float inv2 = rsqrtf(v2 + 1e-5f);
        float o0 = d0 * inv2 * g10 + b10;
        float o1 = d1 * inv2 * g11 + b11;
        if (nb == 0)
            *(float2*)&ws[ATT_OFF + (size_t)grow * EE + e0] = make_float2(o0, o1);
        int slot = (e0 >> 3) ^ (row & 7);
        int base = (row << 7) + (slot << 3) + (e0 & 7);
        As[base] = f2bf(o0);
        As[base + 1] = f2bf(o1);
    }
    __syncthreads();

    const int wr = wave >> 1, wc = wave & 1;
    const int lrow = lane & 15, lq = lane >> 4;
    f32x4 acc[4];
    #pragma unroll
    for (int i = 0; i < 4; i++) acc[i] = (f32x4){0.f, 0.f, 0.f, 0.f};

    #pragma unroll
    for (int ksname = 0; ksname < 4; ++ksname) {
        int G = (ksname << 2) + lq;
        int arow = (wr << 4) + lrow;
        short8 a = *(const short8*)&As[(arow << 7) + ((G ^ (arow & 7)) << 3)];
        #pragma unroll
        for (int nf = 0; nf < 4; ++nf) {
            int e = (wc << 6) + (nf << 4) + lrow;
            short8 bf = *(const short8*)&Bs[((G >> 3) << 13) + (e << 6) + (((G & 7) ^ (e & 7)) << 3)];
            acc[nf] = __builtin_amdgcn_mfma_f32_16x16x32_bf16(a, bf, acc[nf], 0, 0, 0);
        }
    }

    #pragma unroll
    for (int nf = 0; nf < 4; ++nf) {
        int col = (wc << 6) + (nf << 4) + lrow;
        float bias = ff_b1[(nb << 7) + col];
        #pragma unroll
        for (int r = 0; r < 4; ++r)
            ys[(wr << 4) + (lq << 2) + r][col] = fmaxf(acc[nf][r] + bias, 0.f);
    }
    __syncthreads();

    unsigned short* ffhb = (unsigned short*)(ws + FFH_OFF);
    #pragma unroll
    for (int kk = 0; kk < 2; ++kk) {
        int id = t + kk * 256;
        int ssr = id >> 4, fg = id & 15;
        float4 v0 = *(const float4*)&ys[ssr][fg * 8];
        float4 v1 = *(const float4*)&ys[ssr][fg * 8 + 4];
        ushort8 ov;
        ov[0] = f2bf(v0.x); ov[1] = f2bf(v0.y); ov[2] = f2bf(v0.z); ov[3] = f2bf(v0.w);
        ov[4] = f2bf(v1.x); ov[5] = f2bf(v1.y); ov[6] = f2bf(v1.z); ov[7] = f2bf(v1.w);
        int kb = (nb << 1) + (fg >> 3);
        int slot = (fg & 7) ^ (ssr & 7);
        *(ushort8*)&ffhb[(((size_t)(rt * 8 + kb) * 32 + ssr) << 6) + (slot << 3)] = ov;
    }
}

// ---------------- K6: FF2 via MFMA + bias + residual + LN2 + transposed store ----------------
__global__ __launch_bounds__(256) void k6_mfma(const float* __restrict__ b2,
                                               const float* __restrict__ g2, const float* __restrict__ bb2,
                                               float* __restrict__ ws, float* __restrict__ out) {
    __shared__ unsigned short Ab[2][2048];    // 2x4KB
    __shared__ unsigned short Bb[2][8192];    // 2x16KB
    __shared__ float y[32][132];              // 16.9KB
    const int t = threadIdx.x;
    const int wave = t >> 6, lane = t & 63;
    const int rt = blockIdx.x;

    const char* ag = (const char*)((const unsigned short*)(ws + FFH_OFF) + (size_t)rt * 16384);
    const char* bgc = (const char*)(ws + W2FF_BF_OFF);

    auto stage = [&](int kb, int buf) {
        __builtin_amdgcn_global_load_lds(
            (const __attribute__((address_space(1))) unsigned int*)(ag + kb * 4096 + t * 16),
            (__attribute__((address_space(3))) unsigned int*)(&Ab[buf][(t * 16) >> 1]), 16, 0, 0);
        const char* g = bgc + kb * 16384;
        #pragma unroll
        for (int c4 = 0; c4 < 4; ++c4) {
            int off = c4 * 4096 + wave * 1024;
            __builtin_amdgcn_global_load_lds(
                (const __attribute__((address_space(1))) unsigned int*)(g + off + lane * 16),
                (__attribute__((address_space(3))) unsigned int*)(&Bb[buf][off >> 1]), 16, 0, 0);
        }
    };

    const int wr = wave >> 1, wc = wave & 1;
    const int lrow = lane & 15, lq = lane >> 4;
    f32x4 acc[4];
    #pragma unroll
    for (int i = 0; i < 4; i++) acc[i] = (f32x4){0.f, 0.f, 0.f, 0.f};

    stage(0, 0);
    __syncthreads();
    for (int kb = 0; kb < 8; ++kb) {
        int cur = kb & 1;
        if (kb < 7) stage(kb + 1, cur ^ 1);
        #pragma unroll
        for (int ksname = 0; ksname < 2; ++ksname) {
            int G = (ksname << 2) + lq;
            int arow = (wr << 4) + lrow;
            short8 a = *(const short8*)&Ab[cur][(arow << 6) + ((G ^ (arow & 7)) << 3)];
            #pragma unroll
            for (int nf = 0; nf < 4; ++nf) {
                int e = (wc << 6) + (nf << 4) + lrow;
                short8 bf = *(const short8*)&Bb[cur][(e << 6) + ((G ^ (e & 7)) << 3)];
                acc[nf] = __builtin_amdgcn_mfma_f32_16x16x32_bf16(a, bf, acc[nf], 0, 0, 0);
            }
        }
        __syncthreads();
    }

    const int bs0 = rt * 32;
    #pragma unroll
    for (int nf = 0; nf < 4; ++nf) {
        int e = (wc << 6) + (nf << 4) + lrow;
        float bvv = b2[e];
        #pragma unroll
        for (int r = 0; r < 4; ++r) {
            int row = (wr << 4) + (lq << 2) + r;
            y[row][e] = acc[nf][r] + bvv + ws[ATT_OFF + (size_t)(bs0 + row) * EE + e];
        }
    }
    __syncthreads();
    int e0 = lane * 2;
    for (int rr = 0; rr < 8; rr++) {
        int row = wave * 8 + rr;
        float z0 = y[row][e0], z1 = y[row][e0 + 1];
        float mean = wave_sum(z0 + z1) * (1.f / 128.f);
        float d0 = z0 - mean, d1 = z1 - mean;
        float var = wave_sum(d0 * d0 + d1 * d1) * (1.f / 128.f);
        float inv = rsqrtf(var + 1e-5f);
        y[row][e0]     = d0 * inv * g2[e0] + bb2[e0];
        y[row][e0 + 1] = d1 * inv * g2[e0 + 1] + bb2[e0 + 1];
    }
    __syncthreads();
    int b = bs0 >> 10, s0 = bs0 & 1023;
    int sl = t & 31, eg = t >> 5;
    #pragma unroll
    for (int rep = 0; rep < 16; rep++) {
        int e = eg * 16 + rep;
        out[(size_t)b * EE * SS + (size_t)e * SS + s0 + sl] = y[sl][e];
    }
}

extern "C" void kernel_launch(void* const* d_in, const int* in_sizes, int n_in,
                              void* d_out, int out_size, void* d_ws, size_t ws_size,
                              hipStream_t stream) {
    const float* x        = (const float*)d_in[0];
    const float* conv1_w  = (const float*)d_in[1];
    const float* conv1_b  = (const float*)d_in[2];
    const float* bn1_g    = (const float*)d_in[3];
    const float* bn1_b    = (const float*)d_in[4];
    const float* bn1_m    = (const float*)d_in[5];
    const float* bn1_v    = (const float*)d_in[6];
    const float* conv2_w  = (const float*)d_in[7];
    const float* conv2_b  = (const float*)d_in[8];
    const float* bn2_g    = (const float*)d_in[9];
    const float* bn2_b    = (const float*)d_in[10];
    const float* bn2_m    = (const float*)d_in[11];
    const float* bn2_v    = (const float*)d_in[12];
    const float* wq       = (const float*)d_in[13];
    const float* wk       = (const float*)d_in[14];
    const float* wv       = (const float*)d_in[15];
    const float* rel_tab  = (const float*)d_in[16];
    const float* ln_attn_g = (const float*)d_in[17];
    const float* ln_attn_b = (const float*)d_in[18];
    const float* ln1_g    = (const float*)d_in[19];
    const float* ln1_b    = (const float*)d_in[20];
    const float* ln2_g    = (const float*)d_in[21];
    const float* ln2_b    = (const float*)d_in[22];
    const float* ff_w1    = (const float*)d_in[23];
    const float* ff_b1    = (const float*)d_in[24];
    const float* ff_w2    = (const float*)d_in[25];
    const float* ff_b2    = (const float*)d_in[26];

    float* ws  = (float*)d_ws;
    float* out = (float*)d_out;

    hipLaunchKernelGGL(k0_all, dim3(1116), dim3(256), 0, stream,
                       conv1_w, conv1_b, bn1_g, bn1_b, bn1_m, bn1_v,
                       conv2_w, conv2_b, bn2_g, bn2_b, bn2_m, bn2_v,
                       wq, wk, wv, ff_w1, ff_w2, ws);
    hipLaunchKernelGGL(k1_mfma, dim3(128, 4), dim3(256), 0, stream, x, ws);
    hipLaunchKernelGGL(k1b_combine, dim3(1024), dim3(256), 0, stream, ws);
    hipLaunchKernelGGL(k2_mfma, dim3(256, 3), dim3(256), 0, stream, ws);
    hipLaunchKernelGGL(k3_attn, dim3(BB * HH, SS / 64), dim3(256), 0, stream, rel_tab, ws);
    hipLaunchKernelGGL(k5_fused, dim3(256, 4), dim3(256), 0, stream,
                       ln_attn_g, ln_attn_b, ln1_g, ln1_b, ff_b1, ws);
    hipLaunchKernelGGL(k6_mfma, dim3(256), dim3(256), 0, stream, ff_b2, ln2_g, ln2_b, ws, out);
}

// Round 18
// 158.582 us; speedup vs baseline: 1.1489x; 1.0678x over previous
//
#include <hip/hip_runtime.h>
#include <math.h>

// Problem constants
#define BB    8
#define CIN   16
#define SS    1024
#define EE    128
#define HH    8
#define DHH   16
#define O1    512      // E*4
#define DFFN  512
#define K2TOT 8192     // O1*CIN

// Workspace layout (float offsets)
#define PE_OFF    0            // 131072  (S*E)
#define BN1SC_OFF 131072       // 512 (unused; kept)
#define BN1SH_OFF 131584       // 512
#define BN2SC_OFF 132096       // 128
#define BN2SH_OFF 132224       // 128
#define W1P_OFF   133120       // bf16 folded conv1 taps [512 o][8 u]
#define WQKV_BF_OFF 135168     // bf16 wq|wk|wv, each 16384 elems
#define W1FF_BF_OFF 159744     // bf16 ff_w1 [4nb][2kb][128][64]
#define W2FF_BF_OFF 192512     // bf16 ff_w2 [8kb][128][64]
#define XSRC_OFF  262144       // 1048576 (B*S*E) fp32
#define Q_OFF     1310720      // QH: f16 scaled        | k1 partial P0
#define KK_OFF    2359296      // KH                    | k1 partial P1
#define V_OFF     3407872      // VHT                   | k1 partial P2
#define ATTN_OFF  4456448      // (B,S,E) attn out      | k1 partial P3
#define ATT_OFF   5505024      // (B,S,E) post-LN1
#define FFH_OFF   6553600      // k5 bf16 out (2M floats region)
#define W2CONV_BF_OFF 8650752  // bf16 conv2_w (straight k=o*16+c), [128kb][128e][64]
// end: 9175040 floats = 36.7 MB
// NOTE: k1 writes 4 fp32 partials into Q/K/V/ATTN regions; k1b combines into
// XSRC before k2/k3 overwrite those regions. Launch order guarantees safety.

typedef __attribute__((ext_vector_type(8))) short short8;
typedef __attribute__((ext_vector_type(8))) unsigned short ushort8;
typedef __attribute__((ext_vector_type(4))) unsigned short us4;
typedef __attribute__((ext_vector_type(4))) float f32x4;
typedef _Float16 f16_t;
typedef __attribute__((ext_vector_type(4))) _Float16 half4;
typedef __attribute__((ext_vector_type(8))) _Float16 half8;

__device__ __forceinline__ float wave_sum(float v) {
    #pragma unroll
    for (int o = 32; o > 0; o >>= 1) v += __shfl_xor(v, o);
    return v;
}

__device__ __forceinline__ float gelu_exact(float x) {
    return 0.5f * x * (1.0f + erff(x * 0.7071067811865476f));
}

// x - x/(1+exp(2*inner)), constants pre-doubled
__device__ __forceinline__ float gelu_tanh(float x) {
    float x2 = x * x;
    float y = x * fmaf(0.0713548162f, x2, 1.5957691216f);
    float E = __expf(y);
    float r = __builtin_amdgcn_rcpf(E + 1.0f);
    return fmaf(-x, r, x);
}

__device__ __forceinline__ unsigned short f2bf(float f) {   // RNE fp32->bf16
    unsigned int u = __float_as_uint(f);
    unsigned int r = u + 0x7FFFu + ((u >> 16) & 1u);
    return (unsigned short)(r >> 16);
}

__device__ __forceinline__ float bf2f(unsigned short u) {
    return __uint_as_float(((unsigned int)u) << 16);
}

// generic weight cast fp32 -> bf16, chunk-major, pre-swizzled (m173 pattern)
__device__ __forceinline__ void castw_body(const float* __restrict__ src,
                                           unsigned short* __restrict__ dst, int K, int tid) {
    int g = tid & 7, e = (tid >> 3) & 127, rest = tid >> 10;
    int KB = K >> 6;
    int kb = rest % KB, nb = rest / KB;
    int col = nb * 128 + e;
    const float* s = src + (size_t)col * K + kb * 64 + ((g ^ (e & 7)) << 3);
    ushort8 v;
    #pragma unroll
    for (int j = 0; j < 8; j++) v[j] = f2bf(s[j]);
    *(ushort8*)&dst[(size_t)tid << 3] = v;
}

// ---------------- K0: ALL setup jobs fused (independent; branch on blockIdx) ----------------
__global__ __launch_bounds__(256) void k0_all(const float* __restrict__ conv1_w,
                                              const float* __restrict__ conv1_b,
                                              const float* __restrict__ bn1_g,
                                              const float* __restrict__ bn1_b,
                                              const float* __restrict__ bn1_m,
                                              const float* __restrict__ bn1_v,
                                              const float* __restrict__ conv2_w,
                                              const float* __restrict__ conv2_b,
                                              const float* __restrict__ bn2_g,
                                              const float* __restrict__ bn2_b,
                                              const float* __restrict__ bn2_m,
                                              const float* __restrict__ bn2_v,
                                              const float* __restrict__ wq,
                                              const float* __restrict__ wk,
                                              const float* __restrict__ wv,
                                              const float* __restrict__ ff_w1,
                                              const float* __restrict__ ff_w2,
                                              float* __restrict__ ws) {
    int bid = blockIdx.x, t = threadIdx.x;
    if (bid < 512) {                       // PE table
        int idx = bid * 256 + t;
        int s = idx >> 7, e = idx & 127;
        int i = e >> 1;
        float freq = expf((float)(2 * i) * (-9.210340371976184f / 128.0f));
        float ang = (float)s * freq * 0.125f;
        ws[PE_OFF + idx] = (e & 1) ? cosf(ang) : sinf(ang);
    } else if (bid < 515) {                // BN fold
        int u = (bid - 512) * 256 + t;
        if (u < 512) {
            float sc = bn1_g[u] * rsqrtf(bn1_v[u] + 1e-5f);
            ws[BN1SC_OFF + u] = sc;
            ws[BN1SH_OFF + u] = (conv1_b[u] - bn1_m[u]) * sc + bn1_b[u];
        } else if (u < 640) {
            int e = u - 512;
            float sc = bn2_g[e] * rsqrtf(bn2_v[e] + 1e-5f);
            ws[BN2SC_OFF + e] = sc;
            ws[BN2SH_OFF + e] = (conv2_b[e] - bn2_m[e]) * sc + bn2_b[e];
        }
    } else if (bid < 1027) {               // conv2_w cast (straight layout)
        castw_body(conv2_w, (unsigned short*)(ws + W2CONV_BF_OFF), 8192, (bid - 515) * 256 + t);
    } else if (bid < 1035) {
        castw_body(wq, (unsigned short*)(ws + WQKV_BF_OFF), 128, (bid - 1027) * 256 + t);
    } else if (bid < 1043) {
        castw_body(wk, (unsigned short*)(ws + WQKV_BF_OFF) + 16384, 128, (bid - 1035) * 256 + t);
    } else if (bid < 1051) {
        castw_body(wv, (unsigned short*)(ws + WQKV_BF_OFF) + 32768, 128, (bid - 1043) * 256 + t);
    } else if (bid < 1083) {
        castw_body(ff_w1, (unsigned short*)(ws + W1FF_BF_OFF), 128, (bid - 1051) * 256 + t);
    } else if (bid < 1115) {
        castw_body(ff_w2, (unsigned short*)(ws + W2FF_BF_OFF), 512, (bid - 1083) * 256 + t);
    } else {                               // folded bf16 conv1 taps: w1p[o][u] = w1[o][u]*sc1[o]
        unsigned short* w1p = (unsigned short*)(ws + W1P_OFF);
        for (int id = t; id < 4096; id += 256) {
            int o = id >> 3, u = id & 7;
            float sc = bn1_g[o] * rsqrtf(bn1_v[o] + 1e-5f);
            float v = (u < 7) ? conv1_w[o * 7 + u] * sc : 0.f;
            w1p[id] = f2bf(v);
        }
    }
}

// ---------------- K1: fused conv1+bn1+gelu -> conv2 (bf16 MFMA), BARRIER-FREE (R9) ----------
// BM=64, 4 waves; wave w owns output rows [w*16, w*16+16) x ALL 128 e.
// A-fragment computed DIRECTLY in registers in MFMA layout (lane-constant c-set; 56 x-taps
// hoisted). B (w2 bf16, pre-swizzled) streamed global->regs 8+8. No A-LDS, no barriers.
// K-split x4 -> grid (128,4); fp32 partials to Q/K/V/ATTN regions. Best measured: 69.6us.
__global__ __launch_bounds__(256) void k1_mfma(const float* __restrict__ x,
                                               float* __restrict__ ws) {
    __shared__ float xt[CIN][72];                 // 4.5KB: x[b,c, s0-3 .. s0+66]
    __shared__ unsigned short w1ps[128 * 8];      // 2KB (this K-quarter's 128 o-rows)
    __shared__ float sh1s[128];                   // 0.5KB

    const int t = threadIdx.x;
    const int wave = t >> 6, lane = t & 63;
    const int row0 = blockIdx.x * 64;
    const int ksplit = blockIdx.y;                // K-quarter
    const int b = row0 >> 10, s0 = row0 & 1023;
    const int obase = ksplit * 128;

    for (int i = t; i < CIN * 70; i += 256) {
        int c = i / 70, j = i % 70;
        int gs = s0 + j - 3;
        xt[c][j] = (gs >= 0 && gs < SS) ? x[(b * CIN + c) * SS + gs] : 0.f;
    }
    if (t < 128) {
        *(ushort8*)&w1ps[t << 3] =
            ((const ushort8*)((const unsigned short*)(ws + W1P_OFF)))[obase + t];
        sh1s[t] = ws[BN1SH_OFF + obase + t];
    }
    __syncthreads();                              // the ONLY barrier

    const int lrow = lane & 15, lq = lane >> 4;
    const int srow_local = (wave << 4) + lrow;    // 0..63
    const int cbase = (lq & 1) << 3;

    // hoist the 56 x-taps (8 c x 7 u) for this lane's fixed row
    float xv[56];
    #pragma unroll
    for (int c8 = 0; c8 < 8; ++c8)
        #pragma unroll
        for (int u = 0; u < 7; ++u)
            xv[c8 * 7 + u] = xt[cbase + c8][srow_local + u];

    // lane-constant B byte offsets within a 16KB chunk: i = ks2*8+nf
    int boff[16];
    #pragma unroll
    for (int ks2 = 0; ks2 < 2; ++ks2) {
        int G = (ks2 << 2) + lq;
        #pragma unroll
        for (int nf = 0; nf < 8; ++nf) {
            int e = (nf << 4) + lrow;
            boff[ks2 * 8 + nf] = (e << 7) + ((G ^ (e & 7)) << 4);
        }
    }

    const char* w2g = (const char*)(ws + W2CONV_BF_OFF);
    const int olq = lq >> 1;

    auto computeA = [&](int kbl, int ks2) -> short8 {
        int ol = (kbl << 2) + (ks2 << 1) + olq;
        ushort8 w8 = *(const ushort8*)&w1ps[ol << 3];
        float w0 = bf2f(w8[0]), w1_ = bf2f(w8[1]), w2_ = bf2f(w8[2]), w3 = bf2f(w8[3]);
        float w4 = bf2f(w8[4]), w5 = bf2f(w8[5]), w6 = bf2f(w8[6]);
        float sh = sh1s[ol];
        short8 a;
        #pragma unroll
        for (int j = 0; j < 8; ++j) {
            float p = xv[j*7]   * w0 + xv[j*7+1] * w1_ + xv[j*7+2] * w2_ + xv[j*7+3] * w3
                    + xv[j*7+4] * w4 + xv[j*7+5] * w5 + xv[j*7+6] * w6;
            a[j] = (short)f2bf(gelu_tanh(p + sh));
        }
        return a;
    };

    f32x4 acc[8];
    #pragma unroll
    for (int i = 0; i < 8; ++i) acc[i] = (f32x4){0.f, 0.f, 0.f, 0.f};

    #pragma unroll 1
    for (int kbl = 0; kbl < 32; ++kbl) {
        const char* g = w2g + ((size_t)((ksplit << 5) + kbl) << 14);
        short8 bA_[8];
        #pragma unroll
        for (int i = 0; i < 8; ++i) bA_[i] = *(const short8*)(g + boff[i]);
        short8 a0 = computeA(kbl, 0);             // VALU overlaps the loads above
        short8 bB_[8];
        #pragma unroll
        for (int i = 0; i < 8; ++i) bB_[i] = *(const short8*)(g + boff[8 + i]);
        #pragma unroll
        for (int nf = 0; nf < 8; ++nf)
            acc[nf] = __builtin_amdgcn_mfma_f32_16x16x32_bf16(a0, bA_[nf], acc[nf], 0, 0, 0);
        short8 a1 = computeA(kbl, 1);
        #pragma unroll
        for (int nf = 0; nf < 8; ++nf)
            acc[nf] = __builtin_amdgcn_mfma_f32_16x16x32_bf16(a1, bB_[nf], acc[nf], 0, 0, 0);
    }

    // store fp32 partial (no bn2/gelu yet) into Q/K/V/ATTN region for this split
    float* P = ws + Q_OFF + (size_t)ksplit * 1048576;
    #pragma unroll
    for (int nf = 0; nf < 8; ++nf) {
        int e = (nf << 4) + lrow;
        #pragma unroll
        for (int r = 0; r < 4; ++r) {
            int srow = s0 + (wave << 4) + (lq << 2) + r;
            P[(((size_t)(b * SS + srow)) << 7) + e] = acc[nf][r];
        }
    }
}

// ---------------- K1b: combine 4 partials + bn2 + exact gelu -> x_src ----------------
__global__ __launch_bounds__(256) void k1b_combine(float* __restrict__ ws) {
    int f = (blockIdx.x * 256 + threadIdx.x) * 4;   // 1M elems
    int e0 = f & 127;
    float4 p0 = *(const float4*)&ws[Q_OFF + f];
    float4 p1 = *(const float4*)&ws[KK_OFF + f];
    float4 p2 = *(const float4*)&ws[V_OFF + f];
    float4 p3 = *(const float4*)&ws[ATTN_OFF + f];
    float4 sc = *(const float4*)&ws[BN2SC_OFF + e0];
    float4 sh = *(const float4*)&ws[BN2SH_OFF + e0];
    float4 o;
    o.x = gelu_exact(fmaf((p0.x + p1.x) + (p2.x + p3.x), sc.x, sh.x));
    o.y = gelu_exact(fmaf((p0.y + p1.y) + (p2.y + p3.y), sc.y, sh.y));
    o.z = gelu_exact(fmaf((p0.z + p1.z) + (p2.z + p3.z), sc.z, sh.z));
    o.w = gelu_exact(fmaf((p0.w + p1.w) + (p2.w + p3.w), sc.w, sh.w));
    *(float4*)&ws[XSRC_OFF + f] = o;
}

// ---------------- K2: QKV projection via MFMA -> f16 QH(scaled)/KH/VHT (vector stores) ------
__global__ __launch_bounds__(256) void k2_mfma(float* __restrict__ ws) {
    __shared__ unsigned short As[32 * 128];       // 8KB
    __shared__ unsigned short Bs[128 * 128];      // 32KB
    __shared__ float ys[32][132];                 // 16.9KB
    const int t = threadIdx.x;
    const int rt = blockIdx.x, mat = blockIdx.y;
    const int wave = t >> 6, lane = t & 63;

    const char* bg = (const char*)((const unsigned short*)(ws + WQKV_BF_OFF) + mat * 16384);
    #pragma unroll
    for (int c8 = 0; c8 < 8; ++c8) {
        int off = c8 * 4096 + wave * 1024;
        __builtin_amdgcn_global_load_lds(
            (const __attribute__((address_space(1))) unsigned int*)(bg + off + lane * 16),
            (__attribute__((address_space(3))) unsigned int*)(&Bs[off >> 1]), 16, 0, 0);
    }
    const int bs0 = rt * 32;
    const int sl0 = bs0 & 1023;
    for (int i = t; i < 1024; i += 256) {
        int row = i >> 5, d0 = (i & 31) << 2;
        float4 xvv = *(const float4*)&ws[XSRC_OFF + (size_t)(bs0 + row) * EE + d0];
        float4 pv = *(const float4*)&ws[PE_OFF + (size_t)(sl0 + row) * EE + d0];
        us4 o;
        o[0] = f2bf(xvv.x + pv.x); o[1] = f2bf(xvv.y + pv.y);
        o[2] = f2bf(xvv.z + pv.z); o[3] = f2bf(xvv.w + pv.w);
        int slot = (d0 >> 3) ^ (row & 7);
        *(us4*)&As[(row << 7) + (slot << 3) + (d0 & 7)] = o;
    }
    __syncthreads();

    const int wr = wave >> 1, wc = wave & 1;
    const int lrow = lane & 15, lq = lane >> 4;
    f32x4 acc[4];
    #pragma unroll
    for (int i = 0; i < 4; i++) acc[i] = (f32x4){0.f, 0.f, 0.f, 0.f};

    #pragma unroll
    for (int ksname = 0; ksname < 4; ++ksname) {
        int G = (ksname << 2) + lq;
        int arow = (wr << 4) + lrow;
        short8 a = *(const short8*)&As[(arow << 7) + ((G ^ (arow & 7)) << 3)];
        #pragma unroll
        for (int nf = 0; nf < 4; ++nf) {
            int e = (wc << 6) + (nf << 4) + lrow;
            short8 bf = *(const short8*)&Bs[((G >> 3) << 13) + (e << 6) + (((G & 7) ^ (e & 7)) << 3)];
            acc[nf] = __builtin_amdgcn_mfma_f32_16x16x32_bf16(a, bf, acc[nf], 0, 0, 0);
        }
    }

    // C-frag -> LDS (fp32) for vectorized transposed stores
    #pragma unroll
    for (int nf = 0; nf < 4; ++nf) {
        int e = (wc << 6) + (nf << 4) + lrow;
        #pragma unroll
        for (int r = 0; r < 4; ++r)
            ys[(wr << 4) + (lq << 2) + r][e] = acc[nf][r];
    }
    __syncthreads();

    const int b = bs0 >> 10;
    if (mat <= 1) {
        int row = t >> 3, h8 = t & 7;
        float scl = (mat == 0) ? 0.08838834764831845f : 1.0f;
        f16_t* dst = (f16_t*)(ws + (mat == 0 ? Q_OFF : KK_OFF))
                   + (((size_t)(b * HH + h8)) * SS + (sl0 + row)) * DHH;
        half8 v0, v1;
        #pragma unroll
        for (int d = 0; d < 8; d++) v0[d] = (f16_t)(ys[row][h8 * 16 + d] * scl);
        #pragma unroll
        for (int d = 0; d < 8; d++) v1[d] = (f16_t)(ys[row][h8 * 16 + 8 + d] * scl);
        *(half8*)&dst[0] = v0;
        *(half8*)&dst[8] = v1;
    } else {
        int c = t & 127, hf = t >> 7;
        int h8 = c >> 4, d2 = c & 15;
        f16_t* dst = (f16_t*)(ws + V_OFF)
                   + (((size_t)(b * HH + h8)) * DHH + d2) * SS + sl0 + hf * 16;
        half8 v0, v1;
        #pragma unroll
        for (int r = 0; r < 8; r++) v0[r] = (f16_t)ys[hf * 16 + r][c];
        #pragma unroll
        for (int r = 0; r < 8; r++) v1[r] = (f16_t)ys[hf * 16 + 8 + r][c];
        *(half8*)&dst[0] = v0;
        *(half8*)&dst[8] = v1;
    }
}

// ---------------- K3: flash softmax attention + fused rel-bias (mfma 16x16x16 f16) ----------
__global__ __launch_bounds__(256) void k3_attn(const float* __restrict__ rel_tab,
                                               float* __restrict__ ws) {
    __shared__ f16_t rtbl4[4][1088];              // 4 shifted copies for aligned b64 reads
    const int bh = blockIdx.x;                    // b*H + h
    const int h = bh & 7, b = bh >> 3;
    const int i0b = blockIdx.y * 64;
    const int t = threadIdx.x;
    for (int id = t; id < 4 * 1088; id += 256) {
        int p = id / 1088; int j = id - p * 1088;
        int u = j + p;
        float v = (u < 1087) ? rel_tab[(i0b + 1086 - u) * HH + h] : 0.f;
        rtbl4[p][j] = (f16_t)v;
    }
    __syncthreads();

    const int w = t >> 6, lane = t & 63;
    const int q = lane & 15, g = lane >> 4;
    const int r = w * 16 + q;
    const int i = i0b + r;

    const f16_t* QH  = (const f16_t*)(ws + Q_OFF)  + (size_t)bh * SS * DHH;
    const f16_t* KH  = (const f16_t*)(ws + KK_OFF) + (size_t)bh * SS * DHH;
    const f16_t* VHT = (const f16_t*)(ws + V_OFF)  + (size_t)bh * DHH * SS;

    half4 qf = *(const half4*)&QH[(size_t)i * DHH + 4 * g];
    f32x4 o = {0.f, 0.f, 0.f, 0.f};
    f32x4 bv = {0.f, 0.f, 0.f, 0.f};
    const f32x4 zf = {0.f, 0.f, 0.f, 0.f};
    float lp = 0.f;
    const int p4 = (63 - r + 4 * g) & 3;          // vb mod 4, lane-constant

    #pragma unroll 4
    for (int jt = 0; jt < 64; ++jt) {
        half4 kf = *(const half4*)&KH[(size_t)(jt * 16 + q) * DHH + 4 * g];
        f32x4 s = __builtin_amdgcn_mfma_f32_16x16x16f16(kf, qf, zf, 0, 0, 0);
        float p0 = __expf(s[0]), p1 = __expf(s[1]), p2 = __expf(s[2]), p3 = __expf(s[3]);
        lp += (p0 + p1) + (p2 + p3);
        half4 pf;
        pf[0] = (f16_t)p0; pf[1] = (f16_t)p1; pf[2] = (f16_t)p2; pf[3] = (f16_t)p3;
        half4 vf = *(const half4*)&VHT[(size_t)q * SS + jt * 16 + 4 * g];
        o = __builtin_amdgcn_mfma_f32_16x16x16f16(vf, pf, o, 0, 0, 0);
        int vb = 63 - r + jt * 16 + 4 * g;
        half4 bfrag = *(const half4*)&rtbl4[p4][vb & ~3];
        bv = __builtin_amdgcn_mfma_f32_16x16x16f16(vf, bfrag, bv, 0, 0, 0);
    }
    lp += __shfl_xor(lp, 16);
    lp += __shfl_xor(lp, 32);
    float inv = 1.f / lp;
    float4 ov = make_float4(fmaf(o[0], inv, bv[0]), fmaf(o[1], inv, bv[1]),
                            fmaf(o[2], inv, bv[2]), fmaf(o[3], inv, bv[3]));
    *(float4*)&ws[ATTN_OFF + ((size_t)(b * SS) + i) * EE + h * DHH + 4 * g] = ov;
}

// ---------------- K4: LN(attn) -> +x_src -> LN1 -> att ----------------
__global__ __launch_bounds__(256) void k4_ln(const float* __restrict__ g_attn, const float* __restrict__ b_attn,
                                             const float* __restrict__ g1, const float* __restrict__ b1,
                                             float* __restrict__ ws) {
    int row = blockIdx.x * 4 + (threadIdx.x >> 6);
    int lane = threadIdx.x & 63;
    int e0 = lane * 2;
    const float* ain = ws + ATTN_OFF + (size_t)row * EE;
    const float* xsr = ws + XSRC_OFF + (size_t)row * EE;
    float2 a = *(const float2*)(ain + e0);
    float mean = wave_sum(a.x + a.y) * (1.f / 128.f);
    float dx = a.x - mean, dy = a.y - mean;
    float var = wave_sum(dx * dx + dy * dy) * (1.f / 128.f);
    float inv = rsqrtf(var + 1e-5f);
    float n0 = dx * inv * g_attn[e0] + b_attn[e0];
    float n1 = dy * inv * g_attn[e0 + 1] + b_attn[e0 + 1];
    float2 xs2 = *(const float2*)(xsr + e0);
    float z0 = xs2.x + n0, z1 = xs2.y + n1;
    float m2 = wave_sum(z0 + z1) * (1.f / 128.f);
    float d0 = z0 - m2, d1 = z1 - m2;
    float v2 = wave_sum(d0 * d0 + d1 * d1) * (1.f / 128.f);
    float inv2 = rsqrtf(v2 + 1e-5f);
    float o0 = d0 * inv2 * g1[e0] + b1[e0];
    float o1 = d1 * inv2 * g1[e0 + 1] + b1[e0 + 1];
    *(float2*)(ws + ATT_OFF + (size_t)row * EE + e0) = make_float2(o0, o1);
}

// ---------------- K5: FF1 via MFMA + bias + relu -> bf16 swizzled FFHB (vector stores) ------
__global__ __launch_bounds__(256) void k5_mfma(const float* __restrict__ b1,
                                               float* __restrict__ ws) {
    __shared__ unsigned short As[32 * 128];
    __shared__ unsigned short Bs[128 * 128];
    __shared__ float ys[32][132];
    const int t = threadIdx.x;
    const int rt = blockIdx.x, nb = blockIdx.y;
    const int wave = t >> 6, lane = t & 63;

    const char* bg = (const char*)((const unsigned short*)(ws + W1FF_BF_OFF) + nb * 16384);
    #pragma unroll
    for (int c8 = 0; c8 < 8; ++c8) {
        int off = c8 * 4096 + wave * 1024;
        __builtin_amdgcn_global_load_lds(
            (const __attribute__((address_space(1))) unsigned int*)(bg + off + lane * 16),
            (__attribute__((address_space(3))) unsigned int*)(&Bs[off >> 1]), 16, 0, 0);
    }
    const int bs0 = rt * 32;
    for (int i = t; i < 1024; i += 256) {
        int row = i >> 5, d0 = (i & 31) << 2;
        float4 xvv = *(const float4*)&ws[ATT_OFF + (size_t)(bs0 + row) * EE + d0];
        us4 o;
        o[0] = f2bf(xvv.x); o[1] = f2bf(xvv.y); o[2] = f2bf(xvv.z); o[3] = f2bf(xvv.w);
        int slot = (d0 >> 3) ^ (row & 7);
        *(us4*)&As[(row << 7) + (slot << 3) + (d0 & 7)] = o;
    }
    __syncthreads();

    const int wr = wave >> 1, wc = wave & 1;
    const int lrow = lane & 15, lq = lane >> 4;
    f32x4 acc[4];
    #pragma unroll
    for (int i = 0; i < 4; i++) acc[i] = (f32x4){0.f, 0.f, 0.f, 0.f};

    #pragma unroll
    for (int ksname = 0; ksname < 4; ++ksname) {
        int G = (ksname << 2) + lq;
        int arow = (wr << 4) + lrow;
        short8 a = *(const short8*)&As[(arow << 7) + ((G ^ (arow & 7)) << 3)];
        #pragma unroll
        for (int nf = 0; nf < 4; ++nf) {
            int e = (wc << 6) + (nf << 4) + lrow;
            short8 bf = *(const short8*)&Bs[((G >> 3) << 13) + (e << 6) + (((G & 7) ^ (e & 7)) << 3)];
            acc[nf] = __builtin_amdgcn_mfma_f32_16x16x32_bf16(a, bf, acc[nf], 0, 0, 0);
        }
    }

    #pragma unroll
    for (int nf = 0; nf < 4; ++nf) {
        int col = (wc << 6) + (nf << 4) + lrow;
        float bias = b1[(nb << 7) + col];
        #pragma unroll
        for (int r = 0; r < 4; ++r)
            ys[(wr << 4) + (lq << 2) + r][col] = fmaxf(acc[nf][r] + bias, 0.f);
    }
    __syncthreads();

    unsigned short* ffhb = (unsigned short*)(ws + FFH_OFF);
    #pragma unroll
    for (int kk = 0; kk < 2; ++kk) {
        int id = t + kk * 256;
        int ssr = id >> 4, fg = id & 15;
        float4 v0 = *(const float4*)&ys[ssr][fg * 8];
        float4 v1 = *(const float4*)&ys[ssr][fg * 8 + 4];
        ushort8 ov;
        ov[0] = f2bf(v0.x); ov[1] = f2bf(v0.y); ov[2] = f2bf(v0.z); ov[3] = f2bf(v0.w);
        ov[4] = f2bf(v1.x); ov[5] = f2bf(v1.y); ov[6] = f2bf(v1.z); ov[7] = f2bf(v1.w);
        int kb = (nb << 1) + (fg >> 3);
        int slot = (fg & 7) ^ (ssr & 7);
        *(ushort8*)&ffhb[(((size_t)(rt * 8 + kb) * 32 + ssr) << 6) + (slot << 3)] = ov;
    }
}

// ---------------- K6: FF2 via MFMA + bias + residual + LN2 + transposed store ----------------
__global__ __launch_bounds__(256) void k6_mfma(const float* __restrict__ b2,
                                               const float* __restrict__ g2, const float* __restrict__ bb2,
                                               float* __restrict__ ws, float* __restrict__ out) {
    __shared__ unsigned short Ab[2][2048];    // 2x4KB
    __shared__ unsigned short Bb[2][8192];    // 2x16KB
    __shared__ float y[32][132];              // 16.9KB
    const int t = threadIdx.x;
    const int wave = t >> 6, lane = t & 63;
    const int rt = blockIdx.x;

    const char* ag = (const char*)((const unsigned short*)(ws + FFH_OFF) + (size_t)rt * 16384);
    const char* bgc = (const char*)(ws + W2FF_BF_OFF);

    auto stage = [&](int kb, int buf) {
        __builtin_amdgcn_global_load_lds(
            (const __attribute__((address_space(1))) unsigned int*)(ag + kb * 4096 + t * 16),
            (__attribute__((address_space(3))) unsigned int*)(&Ab[buf][(t * 16) >> 1]), 16, 0, 0);
        const char* g = bgc + kb * 16384;
        #pragma unroll
        for (int c4 = 0; c4 < 4; ++c4) {
            int off = c4 * 4096 + wave * 1024;
            __builtin_amdgcn_global_load_lds(
                (const __attribute__((address_space(1))) unsigned int*)(g + off + lane * 16),
                (__attribute__((address_space(3))) unsigned int*)(&Bb[buf][off >> 1]), 16, 0, 0);
        }
    };

    const int wr = wave >> 1, wc = wave & 1;
    const int lrow = lane & 15, lq = lane >> 4;
    f32x4 acc[4];
    #pragma unroll
    for (int i = 0; i < 4; i++) acc[i] = (f32x4){0.f, 0.f, 0.f, 0.f};

    stage(0, 0);
    __syncthreads();
    for (int kb = 0; kb < 8; ++kb) {
        int cur = kb & 1;
        if (kb < 7) stage(kb + 1, cur ^ 1);
        #pragma unroll
        for (int ksname = 0; ksname < 2; ++ksname) {
            int G = (ksname << 2) + lq;
            int arow = (wr << 4) + lrow;
            short8 a = *(const short8*)&Ab[cur][(arow << 6) + ((G ^ (arow & 7)) << 3)];
            #pragma unroll
            for (int nf = 0; nf < 4; ++nf) {
                int e = (wc << 6) + (nf << 4) + lrow;
                short8 bf = *(const short8*)&Bb[cur][(e << 6) + ((G ^ (e & 7)) << 3)];
                acc[nf] = __builtin_amdgcn_mfma_f32_16x16x32_bf16(a, bf, acc[nf], 0, 0, 0);
            }
        }
        __syncthreads();
    }

    const int bs0 = rt * 32;
    #pragma unroll
    for (int nf = 0; nf < 4; ++nf) {
        int e = (wc << 6) + (nf << 4) + lrow;
        float bvv = b2[e];
        #pragma unroll
        for (int r = 0; r < 4; ++r) {
            int row = (wr << 4) + (lq << 2) + r;
            y[row][e] = acc[nf][r] + bvv + ws[ATT_OFF + (size_t)(bs0 + row) * EE + e];
        }
    }
    __syncthreads();
    int e0 = lane * 2;
    for (int rr = 0; rr < 8; rr++) {
        int row = wave * 8 + rr;
        float z0 = y[row][e0], z1 = y[row][e0 + 1];
        float mean = wave_sum(z0 + z1) * (1.f / 128.f);
        float d0 = z0 - mean, d1 = z1 - mean;
        float var = wave_sum(d0 * d0 + d1 * d1) * (1.f / 128.f);
        float inv = rsqrtf(var + 1e-5f);
        y[row][e0]     = d0 * inv * g2[e0] + bb2[e0];
        y[row][e0 + 1] = d1 * inv * g2[e0 + 1] + bb2[e0 + 1];
    }
    __syncthreads();
    int b = bs0 >> 10, s0 = bs0 & 1023;
    int sl = t & 31, eg = t >> 5;
    #pragma unroll
    for (int rep = 0; rep < 16; rep++) {
        int e = eg * 16 + rep;
        out[(size_t)b * EE * SS + (size_t)e * SS + s0 + sl] = y[sl][e];
    }
}

extern "C" void kernel_launch(void* const* d_in, const int* in_sizes, int n_in,
                              void* d_out, int out_size, void* d_ws, size_t ws_size,
                              hipStream_t stream) {
    const float* x        = (const float*)d_in[0];
    const float* conv1_w  = (const float*)d_in[1];
    const float* conv1_b  = (const float*)d_in[2];
    const float* bn1_g    = (const float*)d_in[3];
    const float* bn1_b    = (const float*)d_in[4];
    const float* bn1_m    = (const float*)d_in[5];
    const float* bn1_v    = (const float*)d_in[6];
    const float* conv2_w  = (const float*)d_in[7];
    const float* conv2_b  = (const float*)d_in[8];
    const float* bn2_g    = (const float*)d_in[9];
    const float* bn2_b    = (const float*)d_in[10];
    const float* bn2_m    = (const float*)d_in[11];
    const float* bn2_v    = (const float*)d_in[12];
    const float* wq       = (const float*)d_in[13];
    const float* wk       = (const float*)d_in[14];
    const float* wv       = (const float*)d_in[15];
    const float* rel_tab  = (const float*)d_in[16];
    const float* ln_attn_g = (const float*)d_in[17];
    const float* ln_attn_b = (const float*)d_in[18];
    const float* ln1_g    = (const float*)d_in[19];
    const float* ln1_b    = (const float*)d_in[20];
    const float* ln2_g    = (const float*)d_in[21];
    const float* ln2_b    = (const float*)d_in[22];
    const float* ff_w1    = (const float*)d_in[23];
    const float* ff_b1    = (const float*)d_in[24];
    const float* ff_w2    = (const float*)d_in[25];
    const float* ff_b2    = (const float*)d_in[26];

    float* ws  = (float*)d_ws;
    float* out = (float*)d_out;

    hipLaunchKernelGGL(k0_all, dim3(1116), dim3(256), 0, stream,
                       conv1_w, conv1_b, bn1_g, bn1_b, bn1_m, bn1_v,
                       conv2_w, conv2_b, bn2_g, bn2_b, bn2_m, bn2_v,
                       wq, wk, wv, ff_w1, ff_w2, ws);
    hipLaunchKernelGGL(k1_mfma, dim3(128, 4), dim3(256), 0, stream, x, ws);
    hipLaunchKernelGGL(k1b_combine, dim3(1024), dim3(256), 0, stream, ws);
    hipLaunchKernelGGL(k2_mfma, dim3(256, 3), dim3(256), 0, stream, ws);
    hipLaunchKernelGGL(k3_attn, dim3(BB * HH, SS / 64), dim3(256), 0, stream, rel_tab, ws);
    hipLaunchKernelGGL(k4_ln, dim3(BB * SS / 4), dim3(256), 0, stream, ln_attn_g, ln_attn_b, ln1_g, ln1_b, ws);
    hipLaunchKernelGGL(k5_mfma, dim3(256, 4), dim3(256), 0, stream, ff_b1, ws);
    hipLaunchKernelGGL(k6_mfma, dim3(256), dim3(256), 0, stream, ff_b2, ln2_g, ln2_b, ws, out);
}

// Round 19
// 157.872 us; speedup vs baseline: 1.1541x; 1.0045x over previous
//
#include <hip/hip_runtime.h>
#include <math.h>

// Problem constants
#define BB    8
#define CIN   16
#define SS    1024
#define EE    128
#define HH    8
#define DHH   16
#define O1    512      // E*4
#define DFFN  512
#define K2TOT 8192     // O1*CIN

// Workspace layout (float offsets)
#define PE_OFF    0            // 131072  (S*E)
#define BN1SC_OFF 131072       // 512 (unused; kept)
#define BN1SH_OFF 131584       // 512
#define BN2SC_OFF 132096       // 128
#define BN2SH_OFF 132224       // 128
#define W1P_OFF   133120       // bf16 folded conv1 taps [512 o][8 u]
#define WQKV_BF_OFF 135168     // bf16 wq|wk|wv, each 16384 elems
#define W1FF_BF_OFF 159744     // bf16 ff_w1 [4nb][2kb][128][64]
#define W2FF_BF_OFF 192512     // bf16 ff_w2 [8kb][128][64]
#define XSRC_OFF  262144       // 1048576 (B*S*E) fp32
#define Q_OFF     1310720      // QH: f16 scaled        | k1 partial P0
#define KK_OFF    2359296      // KH                    | k1 partial P1
#define V_OFF     3407872      // VHT                   | k1 partial P2
#define ATTN_OFF  4456448      // (B,S,E) attn out      | k1 partial P3
#define ATT_OFF   5505024      // (B,S,E) post-LN1
#define FFH_OFF   6553600      // k5 bf16 out (2M floats region)
#define W2CONV_BF_OFF 8650752  // bf16 conv2_w (straight k=o*16+c), [128kb][128e][64]
// end: 9175040 floats = 36.7 MB
// NOTE: k1 writes 4 fp32 partials into Q/K/V/ATTN regions; k1b combines into
// XSRC before k2/k3 overwrite those regions. Launch order guarantees safety.

typedef __attribute__((ext_vector_type(8))) short short8;
typedef __attribute__((ext_vector_type(8))) unsigned short ushort8;
typedef __attribute__((ext_vector_type(4))) unsigned short us4;
typedef __attribute__((ext_vector_type(4))) float f32x4;
typedef _Float16 f16_t;
typedef __attribute__((ext_vector_type(4))) _Float16 half4;
typedef __attribute__((ext_vector_type(8))) _Float16 half8;

__device__ __forceinline__ float wave_sum(float v) {
    #pragma unroll
    for (int o = 32; o > 0; o >>= 1) v += __shfl_xor(v, o);
    return v;
}

__device__ __forceinline__ float gelu_exact(float x) {
    return 0.5f * x * (1.0f + erff(x * 0.7071067811865476f));
}

// x - x/(1+exp(2*inner)), constants pre-doubled
__device__ __forceinline__ float gelu_tanh(float x) {
    float x2 = x * x;
    float y = x * fmaf(0.0713548162f, x2, 1.5957691216f);
    float E = __expf(y);
    float r = __builtin_amdgcn_rcpf(E + 1.0f);
    return fmaf(-x, r, x);
}

__device__ __forceinline__ unsigned short f2bf(float f) {   // RNE fp32->bf16
    unsigned int u = __float_as_uint(f);
    unsigned int r = u + 0x7FFFu + ((u >> 16) & 1u);
    return (unsigned short)(r >> 16);
}

__device__ __forceinline__ float bf2f(unsigned short u) {
    return __uint_as_float(((unsigned int)u) << 16);
}

// generic weight cast fp32 -> bf16, chunk-major, pre-swizzled (m173 pattern)
__device__ __forceinline__ void castw_body(const float* __restrict__ src,
                                           unsigned short* __restrict__ dst, int K, int tid) {
    int g = tid & 7, e = (tid >> 3) & 127, rest = tid >> 10;
    int KB = K >> 6;
    int kb = rest % KB, nb = rest / KB;
    int col = nb * 128 + e;
    const float* s = src + (size_t)col * K + kb * 64 + ((g ^ (e & 7)) << 3);
    ushort8 v;
    #pragma unroll
    for (int j = 0; j < 8; j++) v[j] = f2bf(s[j]);
    *(ushort8*)&dst[(size_t)tid << 3] = v;
}

// ---------------- K0: ALL setup jobs fused (independent; branch on blockIdx) ----------------
__global__ __launch_bounds__(256) void k0_all(const float* __restrict__ conv1_w,
                                              const float* __restrict__ conv1_b,
                                              const float* __restrict__ bn1_g,
                                              const float* __restrict__ bn1_b,
                                              const float* __restrict__ bn1_m,
                                              const float* __restrict__ bn1_v,
                                              const float* __restrict__ conv2_w,
                                              const float* __restrict__ conv2_b,
                                              const float* __restrict__ bn2_g,
                                              const float* __restrict__ bn2_b,
                                              const float* __restrict__ bn2_m,
                                              const float* __restrict__ bn2_v,
                                              const float* __restrict__ wq,
                                              const float* __restrict__ wk,
                                              const float* __restrict__ wv,
                                              const float* __restrict__ ff_w1,
                                              const float* __restrict__ ff_w2,
                                              float* __restrict__ ws) {
    int bid = blockIdx.x, t = threadIdx.x;
    if (bid < 512) {                       // PE table (fast-math trig: err ~1e-5 << bf16 lsb)
        int idx = bid * 256 + t;
        int s = idx >> 7, e = idx & 127;
        int i = e >> 1;
        float freq = __expf((float)(2 * i) * (-9.210340371976184f / 128.0f));
        float ang = (float)s * freq * 0.125f;
        ws[PE_OFF + idx] = (e & 1) ? __cosf(ang) : __sinf(ang);
    } else if (bid < 515) {                // BN fold
        int u = (bid - 512) * 256 + t;
        if (u < 512) {
            float sc = bn1_g[u] * rsqrtf(bn1_v[u] + 1e-5f);
            ws[BN1SC_OFF + u] = sc;
            ws[BN1SH_OFF + u] = (conv1_b[u] - bn1_m[u]) * sc + bn1_b[u];
        } else if (u < 640) {
            int e = u - 512;
            float sc = bn2_g[e] * rsqrtf(bn2_v[e] + 1e-5f);
            ws[BN2SC_OFF + e] = sc;
            ws[BN2SH_OFF + e] = (conv2_b[e] - bn2_m[e]) * sc + bn2_b[e];
        }
    } else if (bid < 1027) {               // conv2_w cast (straight layout)
        castw_body(conv2_w, (unsigned short*)(ws + W2CONV_BF_OFF), 8192, (bid - 515) * 256 + t);
    } else if (bid < 1035) {
        castw_body(wq, (unsigned short*)(ws + WQKV_BF_OFF), 128, (bid - 1027) * 256 + t);
    } else if (bid < 1043) {
        castw_body(wk, (unsigned short*)(ws + WQKV_BF_OFF) + 16384, 128, (bid - 1035) * 256 + t);
    } else if (bid < 1051) {
        castw_body(wv, (unsigned short*)(ws + WQKV_BF_OFF) + 32768, 128, (bid - 1043) * 256 + t);
    } else if (bid < 1083) {
        castw_body(ff_w1, (unsigned short*)(ws + W1FF_BF_OFF), 128, (bid - 1051) * 256 + t);
    } else if (bid < 1115) {
        castw_body(ff_w2, (unsigned short*)(ws + W2FF_BF_OFF), 512, (bid - 1083) * 256 + t);
    } else {                               // folded bf16 conv1 taps: w1p[o][u] = w1[o][u]*sc1[o]
        unsigned short* w1p = (unsigned short*)(ws + W1P_OFF);
        for (int id = t; id < 4096; id += 256) {
            int o = id >> 3, u = id & 7;
            float sc = bn1_g[o] * rsqrtf(bn1_v[o] + 1e-5f);
            float v = (u < 7) ? conv1_w[o * 7 + u] * sc : 0.f;
            w1p[id] = f2bf(v);
        }
    }
}

// ---------------- K1: fused conv1+bn1+gelu -> conv2 (bf16 MFMA), BARRIER-FREE (R9) ----------
// BM=64, 4 waves; wave w owns output rows [w*16, w*16+16) x ALL 128 e.
// A-fragment computed DIRECTLY in registers in MFMA layout (lane-constant c-set; 56 x-taps
// hoisted). B (w2 bf16, pre-swizzled) streamed global->regs 8+8. No A-LDS, no barriers.
// K-split x4 -> grid (128,4); fp32 partials to Q/K/V/ATTN regions. Best measured: 69.6us.
__global__ __launch_bounds__(256) void k1_mfma(const float* __restrict__ x,
                                               float* __restrict__ ws) {
    __shared__ float xt[CIN][72];                 // 4.5KB: x[b,c, s0-3 .. s0+66]
    __shared__ unsigned short w1ps[128 * 8];      // 2KB (this K-quarter's 128 o-rows)
    __shared__ float sh1s[128];                   // 0.5KB

    const int t = threadIdx.x;
    const int wave = t >> 6, lane = t & 63;
    const int row0 = blockIdx.x * 64;
    const int ksplit = blockIdx.y;                // K-quarter
    const int b = row0 >> 10, s0 = row0 & 1023;
    const int obase = ksplit * 128;

    for (int i = t; i < CIN * 70; i += 256) {
        int c = i / 70, j = i % 70;
        int gs = s0 + j - 3;
        xt[c][j] = (gs >= 0 && gs < SS) ? x[(b * CIN + c) * SS + gs] : 0.f;
    }
    if (t < 128) {
        *(ushort8*)&w1ps[t << 3] =
            ((const ushort8*)((const unsigned short*)(ws + W1P_OFF)))[obase + t];
        sh1s[t] = ws[BN1SH_OFF + obase + t];
    }
    __syncthreads();                              // the ONLY barrier

    const int lrow = lane & 15, lq = lane >> 4;
    const int srow_local = (wave << 4) + lrow;    // 0..63
    const int cbase = (lq & 1) << 3;

    // hoist the 56 x-taps (8 c x 7 u) for this lane's fixed row
    float xv[56];
    #pragma unroll
    for (int c8 = 0; c8 < 8; ++c8)
        #pragma unroll
        for (int u = 0; u < 7; ++u)
            xv[c8 * 7 + u] = xt[cbase + c8][srow_local + u];

    // lane-constant B byte offsets within a 16KB chunk: i = ks2*8+nf
    int boff[16];
    #pragma unroll
    for (int ks2 = 0; ks2 < 2; ++ks2) {
        int G = (ks2 << 2) + lq;
        #pragma unroll
        for (int nf = 0; nf < 8; ++nf) {
            int e = (nf << 4) + lrow;
            boff[ks2 * 8 + nf] = (e << 7) + ((G ^ (e & 7)) << 4);
        }
    }

    const char* w2g = (const char*)(ws + W2CONV_BF_OFF);
    const int olq = lq >> 1;

    auto computeA = [&](int kbl, int ks2) -> short8 {
        int ol = (kbl << 2) + (ks2 << 1) + olq;
        ushort8 w8 = *(const ushort8*)&w1ps[ol << 3];
        float w0 = bf2f(w8[0]), w1_ = bf2f(w8[1]), w2_ = bf2f(w8[2]), w3 = bf2f(w8[3]);
        float w4 = bf2f(w8[4]), w5 = bf2f(w8[5]), w6 = bf2f(w8[6]);
        float sh = sh1s[ol];
        short8 a;
        #pragma unroll
        for (int j = 0; j < 8; ++j) {
            float p = xv[j*7]   * w0 + xv[j*7+1] * w1_ + xv[j*7+2] * w2_ + xv[j*7+3] * w3
                    + xv[j*7+4] * w4 + xv[j*7+5] * w5 + xv[j*7+6] * w6;
            a[j] = (short)f2bf(gelu_tanh(p + sh));
        }
        return a;
    };

    f32x4 acc[8];
    #pragma unroll
    for (int i = 0; i < 8; ++i) acc[i] = (f32x4){0.f, 0.f, 0.f, 0.f};

    #pragma unroll 1
    for (int kbl = 0; kbl < 32; ++kbl) {
        const char* g = w2g + ((size_t)((ksplit << 5) + kbl) << 14);
        short8 bA_[8];
        #pragma unroll
        for (int i = 0; i < 8; ++i) bA_[i] = *(const short8*)(g + boff[i]);
        short8 a0 = computeA(kbl, 0);             // VALU overlaps the loads above
        short8 bB_[8];
        #pragma unroll
        for (int i = 0; i < 8; ++i) bB_[i] = *(const short8*)(g + boff[8 + i]);
        #pragma unroll
        for (int nf = 0; nf < 8; ++nf)
            acc[nf] = __builtin_amdgcn_mfma_f32_16x16x32_bf16(a0, bA_[nf], acc[nf], 0, 0, 0);
        short8 a1 = computeA(kbl, 1);
        #pragma unroll
        for (int nf = 0; nf < 8; ++nf)
            acc[nf] = __builtin_amdgcn_mfma_f32_16x16x32_bf16(a1, bB_[nf], acc[nf], 0, 0, 0);
    }

    // store fp32 partial (no bn2/gelu yet) into Q/K/V/ATTN region for this split
    float* P = ws + Q_OFF + (size_t)ksplit * 1048576;
    #pragma unroll
    for (int nf = 0; nf < 8; ++nf) {
        int e = (nf << 4) + lrow;
        #pragma unroll
        for (int r = 0; r < 4; ++r) {
            int srow = s0 + (wave << 4) + (lq << 2) + r;
            P[(((size_t)(b * SS + srow)) << 7) + e] = acc[nf][r];
        }
    }
}

// ---------------- K1b: combine 4 partials + bn2 + exact gelu -> x_src ----------------
__global__ __launch_bounds__(256) void k1b_combine(float* __restrict__ ws) {
    int f = (blockIdx.x * 256 + threadIdx.x) * 4;   // 1M elems
    int e0 = f & 127;
    float4 p0 = *(const float4*)&ws[Q_OFF + f];
    float4 p1 = *(const float4*)&ws[KK_OFF + f];
    float4 p2 = *(const float4*)&ws[V_OFF + f];
    float4 p3 = *(const float4*)&ws[ATTN_OFF + f];
    float4 sc = *(const float4*)&ws[BN2SC_OFF + e0];
    float4 sh = *(const float4*)&ws[BN2SH_OFF + e0];
    float4 o;
    o.x = gelu_exact(fmaf((p0.x + p1.x) + (p2.x + p3.x), sc.x, sh.x));
    o.y = gelu_exact(fmaf((p0.y + p1.y) + (p2.y + p3.y), sc.y, sh.y));
    o.z = gelu_exact(fmaf((p0.z + p1.z) + (p2.z + p3.z), sc.z, sh.z));
    o.w = gelu_exact(fmaf((p0.w + p1.w) + (p2.w + p3.w), sc.w, sh.w));
    *(float4*)&ws[XSRC_OFF + f] = o;
}

// ---------------- K2: QKV projection, A staged ONCE, 3 mats looped ----------------
// grid (256): saves 2x A-stage (8MB reads + LDS casts) vs the (256,3) version.
// Next mat's B-stage issues right after the ys-barrier, overlapping the stores.
__global__ __launch_bounds__(256) void k2_mfma(float* __restrict__ ws) {
    __shared__ unsigned short As[32 * 128];       // 8KB
    __shared__ unsigned short Bs[128 * 128];      // 32KB
    __shared__ float ys[32][132];                 // 16.9KB
    const int t = threadIdx.x;
    const int rt = blockIdx.x;
    const int wave = t >> 6, lane = t & 63;

    const unsigned short* wqkv = (const unsigned short*)(ws + WQKV_BF_OFF);
    auto stageB = [&](int mat) {
        const char* bg = (const char*)(wqkv + mat * 16384);
        #pragma unroll
        for (int c8 = 0; c8 < 8; ++c8) {
            int off = c8 * 4096 + wave * 1024;
            __builtin_amdgcn_global_load_lds(
                (const __attribute__((address_space(1))) unsigned int*)(bg + off + lane * 16),
                (__attribute__((address_space(3))) unsigned int*)(&Bs[off >> 1]), 16, 0, 0);
        }
    };

    stageB(0);
    const int bs0 = rt * 32;
    const int sl0 = bs0 & 1023;
    for (int i = t; i < 1024; i += 256) {
        int row = i >> 5, d0 = (i & 31) << 2;
        float4 xvv = *(const float4*)&ws[XSRC_OFF + (size_t)(bs0 + row) * EE + d0];
        float4 pv = *(const float4*)&ws[PE_OFF + (size_t)(sl0 + row) * EE + d0];
        us4 o;
        o[0] = f2bf(xvv.x + pv.x); o[1] = f2bf(xvv.y + pv.y);
        o[2] = f2bf(xvv.z + pv.z); o[3] = f2bf(xvv.w + pv.w);
        int slot = (d0 >> 3) ^ (row & 7);
        *(us4*)&As[(row << 7) + (slot << 3) + (d0 & 7)] = o;
    }
    __syncthreads();                              // A + B(0) ready

    const int wr = wave >> 1, wc = wave & 1;
    const int lrow = lane & 15, lq = lane >> 4;
    const int b = bs0 >> 10;

    #pragma unroll 1
    for (int mat = 0; mat < 3; ++mat) {
        f32x4 acc[4];
        #pragma unroll
        for (int i = 0; i < 4; i++) acc[i] = (f32x4){0.f, 0.f, 0.f, 0.f};

        #pragma unroll
        for (int ksname = 0; ksname < 4; ++ksname) {
            int G = (ksname << 2) + lq;
            int arow = (wr << 4) + lrow;
            short8 a = *(const short8*)&As[(arow << 7) + ((G ^ (arow & 7)) << 3)];
            #pragma unroll
            for (int nf = 0; nf < 4; ++nf) {
                int e = (wc << 6) + (nf << 4) + lrow;
                short8 bf = *(const short8*)&Bs[((G >> 3) << 13) + (e << 6) + (((G & 7) ^ (e & 7)) << 3)];
                acc[nf] = __builtin_amdgcn_mfma_f32_16x16x32_bf16(a, bf, acc[nf], 0, 0, 0);
            }
        }

        // C-frag -> LDS (fp32) for vectorized transposed stores
        #pragma unroll
        for (int nf = 0; nf < 4; ++nf) {
            int e = (wc << 6) + (nf << 4) + lrow;
            #pragma unroll
            for (int r = 0; r < 4; ++r)
                ys[(wr << 4) + (lq << 2) + r][e] = acc[nf][r];
        }
        __syncthreads();                          // ys coherent; MFMA done -> Bs free

        if (mat < 2) stageB(mat + 1);             // async; overlaps the stores below

        if (mat <= 1) {
            int row = t >> 3, h8 = t & 7;
            float scl = (mat == 0) ? 0.08838834764831845f : 1.0f;
            f16_t* dst = (f16_t*)(ws + (mat == 0 ? Q_OFF : KK_OFF))
                       + (((size_t)(b * HH + h8)) * SS + (sl0 + row)) * DHH;
            half8 v0, v1;
            #pragma unroll
            for (int d = 0; d < 8; d++) v0[d] = (f16_t)(ys[row][h8 * 16 + d] * scl);
            #pragma unroll
            for (int d = 0; d < 8; d++) v1[d] = (f16_t)(ys[row][h8 * 16 + 8 + d] * scl);
            *(half8*)&dst[0] = v0;
            *(half8*)&dst[8] = v1;
        } else {
            int c = t & 127, hf = t >> 7;
            int h8 = c >> 4, d2 = c & 15;
            f16_t* dst = (f16_t*)(ws + V_OFF)
                       + (((size_t)(b * HH + h8)) * DHH + d2) * SS + sl0 + hf * 16;
            half8 v0, v1;
            #pragma unroll
            for (int r = 0; r < 8; r++) v0[r] = (f16_t)ys[hf * 16 + r][c];
            #pragma unroll
            for (int r = 0; r < 8; r++) v1[r] = (f16_t)ys[hf * 16 + 8 + r][c];
            *(half8*)&dst[0] = v0;
            *(half8*)&dst[8] = v1;
        }
        if (mat < 2) __syncthreads();             // drains vmcnt: B(mat+1) ready; ys free
    }
}

// ---------------- K3: flash softmax attention + fused rel-bias (mfma 16x16x16 f16) ----------
__global__ __launch_bounds__(256) void k3_attn(const float* __restrict__ rel_tab,
                                               float* __restrict__ ws) {
    __shared__ f16_t rtbl4[4][1088];              // 4 shifted copies for aligned b64 reads
    const int bh = blockIdx.x;                    // b*H + h
    const int h = bh & 7, b = bh >> 3;
    const int i0b = blockIdx.y * 64;
    const int t = threadIdx.x;
    for (int id = t; id < 4 * 1088; id += 256) {
        int p = id / 1088; int j = id - p * 1088;
        int u = j + p;
        float v = (u < 1087) ? rel_tab[(i0b + 1086 - u) * HH + h] : 0.f;
        rtbl4[p][j] = (f16_t)v;
    }
    __syncthreads();

    const int w = t >> 6, lane = t & 63;
    const int q = lane & 15, g = lane >> 4;
    const int r = w * 16 + q;
    const int i = i0b + r;

    const f16_t* QH  = (const f16_t*)(ws + Q_OFF)  + (size_t)bh * SS * DHH;
    const f16_t* KH  = (const f16_t*)(ws + KK_OFF) + (size_t)bh * SS * DHH;
    const f16_t* VHT = (const f16_t*)(ws + V_OFF)  + (size_t)bh * DHH * SS;

    half4 qf = *(const half4*)&QH[(size_t)i * DHH + 4 * g];
    f32x4 o = {0.f, 0.f, 0.f, 0.f};
    f32x4 bv = {0.f, 0.f, 0.f, 0.f};
    const f32x4 zf = {0.f, 0.f, 0.f, 0.f};
    float lp = 0.f;
    const int p4 = (63 - r + 4 * g) & 3;          // vb mod 4, lane-constant

    #pragma unroll 4
    for (int jt = 0; jt < 64; ++jt) {
        half4 kf = *(const half4*)&KH[(size_t)(jt * 16 + q) * DHH + 4 * g];
        f32x4 s = __builtin_amdgcn_mfma_f32_16x16x16f16(kf, qf, zf, 0, 0, 0);
        float p0 = __expf(s[0]), p1 = __expf(s[1]), p2 = __expf(s[2]), p3 = __expf(s[3]);
        lp += (p0 + p1) + (p2 + p3);
        half4 pf;
        pf[0] = (f16_t)p0; pf[1] = (f16_t)p1; pf[2] = (f16_t)p2; pf[3] = (f16_t)p3;
        half4 vf = *(const half4*)&VHT[(size_t)q * SS + jt * 16 + 4 * g];
        o = __builtin_amdgcn_mfma_f32_16x16x16f16(vf, pf, o, 0, 0, 0);
        int vb = 63 - r + jt * 16 + 4 * g;
        half4 bfrag = *(const half4*)&rtbl4[p4][vb & ~3];
        bv = __builtin_amdgcn_mfma_f32_16x16x16f16(vf, bfrag, bv, 0, 0, 0);
    }
    lp += __shfl_xor(lp, 16);
    lp += __shfl_xor(lp, 32);
    float inv = 1.f / lp;
    float4 ov = make_float4(fmaf(o[0], inv, bv[0]), fmaf(o[1], inv, bv[1]),
                            fmaf(o[2], inv, bv[2]), fmaf(o[3], inv, bv[3]));
    *(float4*)&ws[ATTN_OFF + ((size_t)(b * SS) + i) * EE + h * DHH + 4 * g] = ov;
}

// ---------------- K4: LN(attn) -> +x_src -> LN1 -> att ----------------
__global__ __launch_bounds__(256) void k4_ln(const float* __restrict__ g_attn, const float* __restrict__ b_attn,
                                             const float* __restrict__ g1, const float* __restrict__ b1,
                                             float* __restrict__ ws) {
    int row = blockIdx.x * 4 + (threadIdx.x >> 6);
    int lane = threadIdx.x & 63;
    int e0 = lane * 2;
    const float* ain = ws + ATTN_OFF + (size_t)row * EE;
    const float* xsr = ws + XSRC_OFF + (size_t)row * EE;
    float2 a = *(const float2*)(ain + e0);
    float mean = wave_sum(a.x + a.y) * (1.f / 128.f);
    float dx = a.x - mean, dy = a.y - mean;
    float var = wave_sum(dx * dx + dy * dy) * (1.f / 128.f);
    float inv = rsqrtf(var + 1e-5f);
    float n0 = dx * inv * g_attn[e0] + b_attn[e0];
    float n1 = dy * inv * g_attn[e0 + 1] + b_attn[e0 + 1];
    float2 xs2 = *(const float2*)(xsr + e0);
    float z0 = xs2.x + n0, z1 = xs2.y + n1;
    float m2 = wave_sum(z0 + z1) * (1.f / 128.f);
    float d0 = z0 - m2, d1 = z1 - m2;
    float v2 = wave_sum(d0 * d0 + d1 * d1) * (1.f / 128.f);
    float inv2 = rsqrtf(v2 + 1e-5f);
    float o0 = d0 * inv2 * g1[e0] + b1[e0];
    float o1 = d1 * inv2 * g1[e0 + 1] + b1[e0 + 1];
    *(float2*)(ws + ATT_OFF + (size_t)row * EE + e0) = make_float2(o0, o1);
}

// ---------------- K5: FF1 via MFMA + bias + relu -> bf16 swizzled FFHB (vector stores) ------
__global__ __launch_bounds__(256) void k5_mfma(const float* __restrict__ b1,
                                               float* __restrict__ ws) {
    __shared__ unsigned short As[32 * 128];
    __shared__ unsigned short Bs[128 * 128];
    __shared__ float ys[32][132];
    const int t = threadIdx.x;
    const int rt = blockIdx.x, nb = blockIdx.y;
    const int wave = t >> 6, lane = t & 63;

    const char* bg = (const char*)((const unsigned short*)(ws + W1FF_BF_OFF) + nb * 16384);
    #pragma unroll
    for (int c8 = 0; c8 < 8; ++c8) {
        int off = c8 * 4096 + wave * 1024;
        __builtin_amdgcn_global_load_lds(
            (const __attribute__((address_space(1))) unsigned int*)(bg + off + lane * 16),
            (__attribute__((address_space(3))) unsigned int*)(&Bs[off >> 1]), 16, 0, 0);
    }
    const int bs0 = rt * 32;
    for (int i = t; i < 1024; i += 256) {
        int row = i >> 5, d0 = (i & 31) << 2;
        float4 xvv = *(const float4*)&ws[ATT_OFF + (size_t)(bs0 + row) * EE + d0];
        us4 o;
        o[0] = f2bf(xvv.x); o[1] = f2bf(xvv.y); o[2] = f2bf(xvv.z); o[3] = f2bf(xvv.w);
        int slot = (d0 >> 3) ^ (row & 7);
        *(us4*)&As[(row << 7) + (slot << 3) + (d0 & 7)] = o;
    }
    __syncthreads();

    const int wr = wave >> 1, wc = wave & 1;
    const int lrow = lane & 15, lq = lane >> 4;
    f32x4 acc[4];
    #pragma unroll
    for (int i = 0; i < 4; i++) acc[i] = (f32x4){0.f, 0.f, 0.f, 0.f};

    #pragma unroll
    for (int ksname = 0; ksname < 4; ++ksname) {
        int G = (ksname << 2) + lq;
        int arow = (wr << 4) + lrow;
        short8 a = *(const short8*)&As[(arow << 7) + ((G ^ (arow & 7)) << 3)];
        #pragma unroll
        for (int nf = 0; nf < 4; ++nf) {
            int e = (wc << 6) + (nf << 4) + lrow;
            short8 bf = *(const short8*)&Bs[((G >> 3) << 13) + (e << 6) + (((G & 7) ^ (e & 7)) << 3)];
            acc[nf] = __builtin_amdgcn_mfma_f32_16x16x32_bf16(a, bf, acc[nf], 0, 0, 0);
        }
    }

    #pragma unroll
    for (int nf = 0; nf < 4; ++nf) {
        int col = (wc << 6) + (nf << 4) + lrow;
        float bias = b1[(nb << 7) + col];
        #pragma unroll
        for (int r = 0; r < 4; ++r)
            ys[(wr << 4) + (lq << 2) + r][col] = fmaxf(acc[nf][r] + bias, 0.f);
    }
    __syncthreads();

    unsigned short* ffhb = (unsigned short*)(ws + FFH_OFF);
    #pragma unroll
    for (int kk = 0; kk < 2; ++kk) {
        int id = t + kk * 256;
        int ssr = id >> 4, fg = id & 15;
        float4 v0 = *(const float4*)&ys[ssr][fg * 8];
        float4 v1 = *(const float4*)&ys[ssr][fg * 8 + 4];
        ushort8 ov;
        ov[0] = f2bf(v0.x); ov[1] = f2bf(v0.y); ov[2] = f2bf(v0.z); ov[3] = f2bf(v0.w);
        ov[4] = f2bf(v1.x); ov[5] = f2bf(v1.y); ov[6] = f2bf(v1.z); ov[7] = f2bf(v1.w);
        int kb = (nb << 1) + (fg >> 3);
        int slot = (fg & 7) ^ (ssr & 7);
        *(ushort8*)&ffhb[(((size_t)(rt * 8 + kb) * 32 + ssr) << 6) + (slot << 3)] = ov;
    }
}

// ---------------- K6: FF2 via MFMA + bias + residual + LN2 + transposed store ----------------
__global__ __launch_bounds__(256) void k6_mfma(const float* __restrict__ b2,
                                               const float* __restrict__ g2, const float* __restrict__ bb2,
                                               float* __restrict__ ws, float* __restrict__ out) {
    __shared__ unsigned short Ab[2][2048];    // 2x4KB
    __shared__ unsigned short Bb[2][8192];    // 2x16KB
    __shared__ float y[32][132];              // 16.9KB
    const int t = threadIdx.x;
    const int wave = t >> 6, lane = t & 63;
    const int rt = blockIdx.x;

    const char* ag = (const char*)((const unsigned short*)(ws + FFH_OFF) + (size_t)rt * 16384);
    const char* bgc = (const char*)(ws + W2FF_BF_OFF);

    auto stage = [&](int kb, int buf) {
        __builtin_amdgcn_global_load_lds(
            (const __attribute__((address_space(1))) unsigned int*)(ag + kb * 4096 + t * 16),
            (__attribute__((address_space(3))) unsigned int*)(&Ab[buf][(t * 16) >> 1]), 16, 0, 0);
        const char* g = bgc + kb * 16384;
        #pragma unroll
        for (int c4 = 0; c4 < 4; ++c4) {
            int off = c4 * 4096 + wave * 1024;
            __builtin_amdgcn_global_load_lds(
                (const __attribute__((address_space(1))) unsigned int*)(g + off + lane * 16),
                (__attribute__((address_space(3))) unsigned int*)(&Bb[buf][off >> 1]), 16, 0, 0);
        }
    };

    const int wr = wave >> 1, wc = wave & 1;
    const int lrow = lane & 15, lq = lane >> 4;
    f32x4 acc[4];
    #pragma unroll
    for (int i = 0; i < 4; i++) acc[i] = (f32x4){0.f, 0.f, 0.f, 0.f};

    stage(0, 0);
    __syncthreads();
    for (int kb = 0; kb < 8; ++kb) {
        int cur = kb & 1;
        if (kb < 7) stage(kb + 1, cur ^ 1);
        #pragma unroll
        for (int ksname = 0; ksname < 2; ++ksname) {
            int G = (ksname << 2) + lq;
            int arow = (wr << 4) + lrow;
            short8 a = *(const short8*)&Ab[cur][(arow << 6) + ((G ^ (arow & 7)) << 3)];
            #pragma unroll
            for (int nf = 0; nf < 4; ++nf) {
                int e = (wc << 6) + (nf << 4) + lrow;
                short8 bf = *(const short8*)&Bb[cur][(e << 6) + ((G ^ (e & 7)) << 3)];
                acc[nf] = __builtin_amdgcn_mfma_f32_16x16x32_bf16(a, bf, acc[nf], 0, 0, 0);
            }
        }
        __syncthreads();
    }

    const int bs0 = rt * 32;
    #pragma unroll
    for (int nf = 0; nf < 4; ++nf) {
        int e = (wc << 6) + (nf << 4) + lrow;
        float bvv = b2[e];
        #pragma unroll
        for (int r = 0; r < 4; ++r) {
            int row = (wr << 4) + (lq << 2) + r;
            y[row][e] = acc[nf][r] + bvv + ws[ATT_OFF + (size_t)(bs0 + row) * EE + e];
        }
    }
    __syncthreads();
    int e0 = lane * 2;
    for (int rr = 0; rr < 8; rr++) {
        int row = wave * 8 + rr;
        float z0 = y[row][e0], z1 = y[row][e0 + 1];
        float mean = wave_sum(z0 + z1) * (1.f / 128.f);
        float d0 = z0 - mean, d1 = z1 - mean;
        float var = wave_sum(d0 * d0 + d1 * d1) * (1.f / 128.f);
        float inv = rsqrtf(var + 1e-5f);
        y[row][e0]     = d0 * inv * g2[e0] + bb2[e0];
        y[row][e0 + 1] = d1 * inv * g2[e0 + 1] + bb2[e0 + 1];
    }
    __syncthreads();
    int b = bs0 >> 10, s0 = bs0 & 1023;
    int sl = t & 31, eg = t >> 5;
    #pragma unroll
    for (int rep = 0; rep < 16; rep++) {
        int e = eg * 16 + rep;
        out[(size_t)b * EE * SS + (size_t)e * SS + s0 + sl] = y[sl][e];
    }
}

extern "C" void kernel_launch(void* const* d_in, const int* in_sizes, int n_in,
                              void* d_out, int out_size, void* d_ws, size_t ws_size,
                              hipStream_t stream) {
    const float* x        = (const float*)d_in[0];
    const float* conv1_w  = (const float*)d_in[1];
    const float* conv1_b  = (const float*)d_in[2];
    const float* bn1_g    = (const float*)d_in[3];
    const float* bn1_b    = (const float*)d_in[4];
    const float* bn1_m    = (const float*)d_in[5];
    const float* bn1_v    = (const float*)d_in[6];
    const float* conv2_w  = (const float*)d_in[7];
    const float* conv2_b  = (const float*)d_in[8];
    const float* bn2_g    = (const float*)d_in[9];
    const float* bn2_b    = (const float*)d_in[10];
    const float* bn2_m    = (const float*)d_in[11];
    const float* bn2_v    = (const float*)d_in[12];
    const float* wq       = (const float*)d_in[13];
    const float* wk       = (const float*)d_in[14];
    const float* wv       = (const float*)d_in[15];
    const float* rel_tab  = (const float*)d_in[16];
    const float* ln_attn_g = (const float*)d_in[17];
    const float* ln_attn_b = (const float*)d_in[18];
    const float* ln1_g    = (const float*)d_in[19];
    const float* ln1_b    = (const float*)d_in[20];
    const float* ln2_g    = (const float*)d_in[21];
    const float* ln2_b    = (const float*)d_in[22];
    const float* ff_w1    = (const float*)d_in[23];
    const float* ff_b1    = (const float*)d_in[24];
    const float* ff_w2    = (const float*)d_in[25];
    const float* ff_b2    = (const float*)d_in[26];

    float* ws  = (float*)d_ws;
    float* out = (float*)d_out;

    hipLaunchKernelGGL(k0_all, dim3(1116), dim3(256), 0, stream,
                       conv1_w, conv1_b, bn1_g, bn1_b, bn1_m, bn1_v,
                       conv2_w, conv2_b, bn2_g, bn2_b, bn2_m, bn2_v,
                       wq, wk, wv, ff_w1, ff_w2, ws);
    hipLaunchKernelGGL(k1_mfma, dim3(128, 4), dim3(256), 0, stream, x, ws);
    hipLaunchKernelGGL(k1b_combine, dim3(1024), dim3(256), 0, stream, ws);
    hipLaunchKernelGGL(k2_mfma, dim3(256), dim3(256), 0, stream, ws);
    hipLaunchKernelGGL(k3_attn, dim3(BB * HH, SS / 64), dim3(256), 0, stream, rel_tab, ws);
    hipLaunchKernelGGL(k4_ln, dim3(BB * SS / 4), dim3(256), 0, stream, ln_attn_g, ln_attn_b, ln1_g, ln1_b, ws);
    hipLaunchKernelGGL(k5_mfma, dim3(256, 4), dim3(256), 0, stream, ff_b1, ws);
    hipLaunchKernelGGL(k6_mfma, dim3(256), dim3(256), 0, stream, ff_b2, ln2_g, ln2_b, ws, out);
}